// Round 1
// 1588.434 us; speedup vs baseline: 1.0336x; 1.0336x over previous
//
#include <hip/hip_runtime.h>
#include <stdint.h>

// MHA forward: B=4, L=2048, C=512, H=8, D=512 (HD=4096), TEMP=1, EPS=1e-5
// outputs: out0 = layernorm(ctx@Wo + bo + q)  [4,2048,512] fp32
//          atten = softmax(mask(qh@khT))      [32,2048,2048] fp32
//
// R1 change vs baseline (1642 us): kill the OP_F32 staging path everywhere.
//   - q,k,v pre-converted to f16 once (bit-identical to converting at frag load)
//   - softmax emits f16 sidecar atten16; PV GEMM reads f16 A (half bytes, fast path)
//   - all 7 GEMMs now pure-f16 global_load_lds staging
// Numerics unchanged: every MFMA sees the same f16 inputs as before.
// Workspace peak: 440 MB (fills observed at ~2.2 GB, so safe).

typedef unsigned short u16;
typedef _Float16 f16;
typedef __attribute__((ext_vector_type(4))) _Float16 f16x4;
typedef __attribute__((ext_vector_type(8))) _Float16 f16x8;
typedef __attribute__((ext_vector_type(4))) float f32x4;

#define EPI_QKH    0
#define EPI_VHT    1
#define EPI_SCORES 2
#define EPI_CTX    3
#define EPI_OUT    4

__device__ __forceinline__ f32x4 mfma16(f16x8 a, f16x8 b, f32x4 c) {
  return __builtin_amdgcn_mfma_f32_16x16x32_f16(a, b, c, 0, 0, 0);
}

// ---- staging: f16 tile 128x32 row-major via global_load_lds (width 16) ----
__device__ __forceinline__ void stage_tile_f16(const char* gbase, size_t grow, char* lds, int tid) {
  const int lane = tid & 63, wave = tid >> 6;
#pragma unroll
  for (int c = 0; c < 2; ++c) {            // 8 KB tile = 8 chunks of 1 KB, 2/wave
    int chunk = wave * 2 + c;
    int off = chunk * 1024 + lane * 16;    // 64 B per row
    int r = off >> 6;
    int cb = off & 63;
    const char* g = gbase + (size_t)r * grow + cb;
    __builtin_amdgcn_global_load_lds(
        (__attribute__((address_space(1))) void*)g,
        (__attribute__((address_space(3))) void*)(lds + chunk * 1024),
        16, 0, 0);
  }
}

// ---- fragment load (A and B share layout: row = lane&15, k = quad*8+j) ----
__device__ __forceinline__ f16x8 load_frag16(const char* lds, int row, int kq) {
  return *(const f16x8*)(lds + ((size_t)row * 32 + kq) * 2);
}

// ---- generic 128x128 MFMA GEMM: C[m][n] = sum_k A[m][k]*B[n][k] (+epilogue) ----
template<int EPI>
__global__ __launch_bounds__(256, 2)
void gemm_k(const char* __restrict__ A, const char* __restrict__ B,
            int lda, int ldb, int K,
            char* __restrict__ C0,
            const float* __restrict__ bias, const float* __restrict__ resid) {
  __shared__ alignas(16) char smem[16384];
  char* sA = smem;
  char* sB = smem + 8192;

  const int tid = threadIdx.x, lane = tid & 63, wave = tid >> 6;
  const int wm = wave >> 1, wn = wave & 1;
  const int m0 = blockIdx.x * 128, n0 = blockIdx.y * 128;

  const char* pA = A; const char* pB = B;
  if constexpr (EPI == EPI_SCORES) {
    int z = blockIdx.z, h = z >> 2, b = z & 3;
    size_t e2 = ((size_t)b * 2048 * 4096 + (size_t)h * 512) * 2;
    pA += e2; pB += e2;
  } else if constexpr (EPI == EPI_CTX) {
    int z = blockIdx.z, h = z >> 2, b = z & 3;
    pA += ((size_t)z << 22) * 2;                       // atten16 block (f16)
    pB += ((size_t)(b * 8 + h) * 512 * 2048) * 2;      // vhT block (f16)
  }

  f32x4 acc[4][4];
#pragma unroll
  for (int i = 0; i < 4; ++i)
#pragma unroll
    for (int j = 0; j < 4; ++j) acc[i][j] = (f32x4){0.f, 0.f, 0.f, 0.f};

  for (int k0 = 0; k0 < K; k0 += 32) {
    stage_tile_f16(pA + ((size_t)m0 * lda + k0) * 2, (size_t)lda * 2, sA, tid);
    stage_tile_f16(pB + ((size_t)n0 * ldb + k0) * 2, (size_t)ldb * 2, sB, tid);
    __syncthreads();

    const int kq = (lane >> 4) * 8, l15 = lane & 15;
    f16x8 af[4], bf[4];
#pragma unroll
    for (int mi = 0; mi < 4; ++mi)
      af[mi] = load_frag16(sA, wm * 64 + mi * 16 + l15, kq);
#pragma unroll
    for (int ni = 0; ni < 4; ++ni)
      bf[ni] = load_frag16(sB, wn * 64 + ni * 16 + l15, kq);

#pragma unroll
    for (int mi = 0; mi < 4; ++mi)
#pragma unroll
      for (int ni = 0; ni < 4; ++ni)
        acc[mi][ni] = mfma16(af[mi], bf[ni], acc[mi][ni]);
    __syncthreads();
  }

  // epilogue: C/D layout col=lane&15, row=quad*4+reg (m89/m91-verified)
  const int l15 = lane & 15, quad = lane >> 4;
#pragma unroll
  for (int mi = 0; mi < 4; ++mi)
#pragma unroll
    for (int ni = 0; ni < 4; ++ni)
#pragma unroll
      for (int r = 0; r < 4; ++r) {
        int m = m0 + wm * 64 + mi * 16 + quad * 4 + r;
        int n = n0 + wn * 64 + ni * 16 + l15;
        float v = acc[mi][ni][r];
        if constexpr (EPI == EPI_QKH) {
          v += bias[n];
          ((f16*)C0)[(size_t)m * 4096 + n] = (f16)v;
        } else if constexpr (EPI == EPI_VHT) {
          v += bias[m];  // m is hd index
          int hh = m >> 9, d = m & 511, bb = n >> 11, ll = n & 2047;
          ((f16*)C0)[(((size_t)(bb * 8 + hh) * 512 + d) << 11) + ll] = (f16)v;
        } else if constexpr (EPI == EPI_SCORES) {
          int z = blockIdx.z;
          ((float*)C0)[((size_t)z << 22) + ((size_t)m << 11) + n] = v;
        } else if constexpr (EPI == EPI_CTX) {
          int z = blockIdx.z, hh = z >> 2, bb = z & 3;
          ((f16*)C0)[((size_t)(bb * 2048 + m) << 12) + hh * 512 + n] = (f16)v;
        } else {  // EPI_OUT
          v += bias[n] + resid[((size_t)m << 9) + n];
          ((float*)C0)[((size_t)m << 9) + n] = v;
        }
      }
}

// ---- weight transpose + f16 convert: out[c*rows+r] = in[r*cols+c] ----
__global__ __launch_bounds__(256)
void transpose_cvt_k(const float* __restrict__ in, f16* __restrict__ T,
                     int rows_in, int cols_in) {
  int idx = blockIdx.x * 256 + threadIdx.x;
  if (idx >= rows_in * cols_in) return;
  int c = idx / rows_in, r = idx - c * rows_in;
  T[idx] = (f16)in[(size_t)r * cols_in + c];
}

// ---- fp32 -> f16 elementwise (4 floats/thread) ----
__global__ __launch_bounds__(256)
void cvt_f16_k(const float* __restrict__ in, f16* __restrict__ out) {
  int i = blockIdx.x * 256 + threadIdx.x;
  float4 v = ((const float4*)in)[i];
  f16x4 h;
  h[0] = (f16)v.x; h[1] = (f16)v.y; h[2] = (f16)v.z; h[3] = (f16)v.w;
  ((f16x4*)out)[i] = h;
}

// ---- mask int32 -> int8 ----
__global__ __launch_bounds__(256)
void maskprep_k(const int* __restrict__ m32, unsigned char* __restrict__ m8) {
  int i = blockIdx.x * 256 + threadIdx.x;   // 4,194,304 int4s
  int4 v = ((const int4*)m32)[i];
  uchar4 c;
  c.x = (unsigned char)v.x; c.y = (unsigned char)v.y;
  c.z = (unsigned char)v.z; c.w = (unsigned char)v.w;
  ((uchar4*)m8)[i] = c;
}

// ---- masked in-place row softmax over 2048 cols, + f16 sidecar for PV ----
__global__ __launch_bounds__(256)
void softmax_k(float* __restrict__ att, const unsigned char* __restrict__ m8,
               f16* __restrict__ att16) {
  __shared__ float sm[4];
  int t = threadIdx.x, lane = t & 63, wave = t >> 6;
  size_t r = blockIdx.x;
  int z = (int)(r >> 11), m = (int)(r & 2047), b = z & 3;
  float4* row = (float4*)(att + (r << 11));
  const uchar4* mrow = (const uchar4*)(m8 + (((size_t)b << 22) + ((size_t)m << 11)));
  float4 a = row[t], c = row[t + 256];
  uchar4 ma = mrow[t], mc = mrow[t + 256];
  if (ma.x) a.x = -1e30f; if (ma.y) a.y = -1e30f;
  if (ma.z) a.z = -1e30f; if (ma.w) a.w = -1e30f;
  if (mc.x) c.x = -1e30f; if (mc.y) c.y = -1e30f;
  if (mc.z) c.z = -1e30f; if (mc.w) c.w = -1e30f;
  float mx = fmaxf(fmaxf(fmaxf(a.x, a.y), fmaxf(a.z, a.w)),
                   fmaxf(fmaxf(c.x, c.y), fmaxf(c.z, c.w)));
#pragma unroll
  for (int o = 32; o > 0; o >>= 1) mx = fmaxf(mx, __shfl_xor(mx, o));
  if (lane == 0) sm[wave] = mx;
  __syncthreads();
  mx = fmaxf(fmaxf(sm[0], sm[1]), fmaxf(sm[2], sm[3]));
  a.x = __expf(a.x - mx); a.y = __expf(a.y - mx);
  a.z = __expf(a.z - mx); a.w = __expf(a.w - mx);
  c.x = __expf(c.x - mx); c.y = __expf(c.y - mx);
  c.z = __expf(c.z - mx); c.w = __expf(c.w - mx);
  float s = a.x + a.y + a.z + a.w + c.x + c.y + c.z + c.w;
#pragma unroll
  for (int o = 32; o > 0; o >>= 1) s += __shfl_xor(s, o);
  __syncthreads();
  if (lane == 0) sm[wave] = s;
  __syncthreads();
  s = sm[0] + sm[1] + sm[2] + sm[3];
  float inv = 1.0f / s;
  a.x *= inv; a.y *= inv; a.z *= inv; a.w *= inv;
  c.x *= inv; c.y *= inv; c.z *= inv; c.w *= inv;
  row[t] = a; row[t + 256] = c;
  f16x4* r16 = (f16x4*)(att16 + (r << 11));
  f16x4 ha, hc;
  ha[0] = (f16)a.x; ha[1] = (f16)a.y; ha[2] = (f16)a.z; ha[3] = (f16)a.w;
  hc[0] = (f16)c.x; hc[1] = (f16)c.y; hc[2] = (f16)c.z; hc[3] = (f16)c.w;
  r16[t] = ha; r16[t + 256] = hc;
}

// ---- layernorm over last dim (512), biased var, eps=1e-5 ----
__global__ __launch_bounds__(256)
void ln_k(const float* __restrict__ x, const float* __restrict__ gamma,
          const float* __restrict__ beta, float* __restrict__ out) {
  __shared__ float s1[4], s2[4];
  int t = threadIdx.x, lane = t & 63, wave = t >> 6;
  size_t base = (size_t)blockIdx.x << 9;
  float2 v = ((const float2*)(x + base))[t];
  float s = v.x + v.y;
  float q = v.x * v.x + v.y * v.y;
#pragma unroll
  for (int o = 32; o > 0; o >>= 1) { s += __shfl_xor(s, o); q += __shfl_xor(q, o); }
  if (lane == 0) { s1[wave] = s; s2[wave] = q; }
  __syncthreads();
  s = s1[0] + s1[1] + s1[2] + s1[3];
  q = s2[0] + s2[1] + s2[2] + s2[3];
  float mu = s * (1.0f / 512.0f);
  float var = q * (1.0f / 512.0f) - mu * mu;
  float rs = rsqrtf(var + 1e-5f);
  float2 g = ((const float2*)gamma)[t];
  float2 bb = ((const float2*)beta)[t];
  float2 o2;
  o2.x = (v.x - mu) * rs * g.x + bb.x;
  o2.y = (v.y - mu) * rs * g.y + bb.y;
  ((float2*)(out + base))[t] = o2;
}

extern "C" void kernel_launch(void* const* d_in, const int* in_sizes, int n_in,
                              void* d_out, int out_size, void* d_ws, size_t ws_size,
                              hipStream_t stream) {
  (void)in_sizes; (void)n_in; (void)out_size; (void)ws_size;
  const float* q     = (const float*)d_in[0];
  const float* k     = (const float*)d_in[1];
  const float* v     = (const float*)d_in[2];
  const int*   mask  = (const int*)d_in[3];
  const float* Wq    = (const float*)d_in[4];
  const float* bq    = (const float*)d_in[5];
  const float* Wk    = (const float*)d_in[6];
  const float* bk    = (const float*)d_in[7];
  const float* Wv    = (const float*)d_in[8];
  const float* bv    = (const float*)d_in[9];
  const float* Wo    = (const float*)d_in[10];
  const float* bo    = (const float*)d_in[11];
  const float* gamma = (const float*)d_in[12];
  const float* beta  = (const float*)d_in[13];

  float* out0  = (float*)d_out;
  float* atten = out0 + (size_t)4 * 2048 * 512;

  char* ws = (char*)d_ws;
  const size_t MB = 1024ull * 1024ull;
  // liveness-packed layout (peak 440 MB):
  f16* WqT  = (f16*)(ws + 0 * MB);     // [4096x512] 4 MB
  f16* WkT  = (f16*)(ws + 4 * MB);
  f16* WvT  = (f16*)(ws + 8 * MB);
  f16* WoT  = (f16*)(ws + 12 * MB);    // [512x4096]
  unsigned char* mask8 = (unsigned char*)(ws + 16 * MB);  // 16 MB
  f16* q16  = (f16*)(ws + 32 * MB);    // 8 MB each, dead after projections
  f16* k16  = (f16*)(ws + 40 * MB);
  f16* v16  = (f16*)(ws + 48 * MB);
  f16* vhT  = (f16*)(ws + 56 * MB);    // [b][h][d][l] 64 MB, live thru PV
  f16* atten16 = (f16*)(ws + 120 * MB);// [z][l][l] 256 MB, softmax -> PV
  f16* qh   = (f16*)(ws + 120 * MB);   // 64 MB, dead before atten16 written
  f16* kh   = (f16*)(ws + 184 * MB);   // 64 MB, dead before atten16 written
  f16* ctx  = (f16*)(ws + 376 * MB);   // [8192x4096] 64 MB, ends 440 MB
  float* xbuf = (float*)(ws + 120 * MB); // 16 MB fp32, after atten16 dead

  // prep: weight transposes to NxK f16, mask to int8, q/k/v to f16
  transpose_cvt_k<<<8192, 256, 0, stream>>>(Wq, WqT, 512, 4096);
  transpose_cvt_k<<<8192, 256, 0, stream>>>(Wk, WkT, 512, 4096);
  transpose_cvt_k<<<8192, 256, 0, stream>>>(Wv, WvT, 512, 4096);
  transpose_cvt_k<<<8192, 256, 0, stream>>>(Wo, WoT, 4096, 512);
  maskprep_k<<<16384, 256, 0, stream>>>(mask, mask8);
  cvt_f16_k<<<4096, 256, 0, stream>>>(q, q16);
  cvt_f16_k<<<4096, 256, 0, stream>>>(k, k16);
  cvt_f16_k<<<4096, 256, 0, stream>>>(v, v16);

  // Q/K projections -> f16 (pure f16 path now)
  gemm_k<EPI_QKH><<<dim3(64, 32, 1), 256, 0, stream>>>(
      (const char*)q16, (const char*)WqT, 512, 512, 512, (char*)qh, bq, nullptr);
  gemm_k<EPI_QKH><<<dim3(64, 32, 1), 256, 0, stream>>>(
      (const char*)k16, (const char*)WkT, 512, 512, 512, (char*)kh, bk, nullptr);

  // V projection, written directly transposed: vhT[b][h][d][l]
  gemm_k<EPI_VHT><<<dim3(32, 64, 1), 256, 0, stream>>>(
      (const char*)WvT, (const char*)v16, 512, 512, 512, (char*)vhT, bv, nullptr);

  // raw scores = qh @ kh^T per (h,b) -> d_out atten region (fp32)
  gemm_k<EPI_SCORES><<<dim3(16, 16, 32), 256, 0, stream>>>(
      (const char*)qh, (const char*)kh, 4096, 4096, 512, (char*)atten, nullptr, nullptr);

  // masked softmax in place on d_out + f16 sidecar for PV
  softmax_k<<<65536, 256, 0, stream>>>(atten, mask8, atten16);

  // ctx = atten16 @ vh per (h,b)  (pure f16 path now)
  gemm_k<EPI_CTX><<<dim3(16, 4, 32), 256, 0, stream>>>(
      (const char*)atten16, (const char*)vhT, 2048, 2048, 2048, (char*)ctx, nullptr, nullptr);

  // out = ctx @ Wo + bo + residual(q) -> xbuf
  gemm_k<EPI_OUT><<<dim3(64, 4, 1), 256, 0, stream>>>(
      (const char*)ctx, (const char*)WoT, 4096, 4096, 4096, (char*)xbuf, bo, q);

  // layernorm -> out0
  ln_k<<<8192, 256, 0, stream>>>(xbuf, gamma, beta, out0);
}

// Round 2
// 1563.285 us; speedup vs baseline: 1.0503x; 1.0161x over previous
//
#include <hip/hip_runtime.h>
#include <stdint.h>

// MHA forward: B=4, L=2048, C=512, H=8, D=512 (HD=4096), TEMP=1, EPS=1e-5
// outputs: out0 = layernorm(ctx@Wo + bo + q)  [4,2048,512] fp32
//          atten = softmax(mask(qh@khT))      [32,2048,2048] fp32
//
// R2 change vs R1 (1588 us): GEMM loop 1-phase -> 2-phase double-buffered.
//   - LDS 16KB -> 2x16KB; prefetch tile t+1 issued BEFORE ds_read/MFMA of t
//   - 1 barrier per K-step instead of 2 (HBM latency hides under compute)
// Numerics bit-identical to R1 (same MFMA inputs, same epilogues).
// Workspace peak: 440 MB.

typedef unsigned short u16;
typedef _Float16 f16;
typedef __attribute__((ext_vector_type(4))) _Float16 f16x4;
typedef __attribute__((ext_vector_type(8))) _Float16 f16x8;
typedef __attribute__((ext_vector_type(4))) float f32x4;

#define EPI_QKH    0
#define EPI_VHT    1
#define EPI_SCORES 2
#define EPI_CTX    3
#define EPI_OUT    4

__device__ __forceinline__ f32x4 mfma16(f16x8 a, f16x8 b, f32x4 c) {
  return __builtin_amdgcn_mfma_f32_16x16x32_f16(a, b, c, 0, 0, 0);
}

// ---- staging: f16 tile 128x32 row-major via global_load_lds (width 16) ----
__device__ __forceinline__ void stage_tile_f16(const char* gbase, size_t grow, char* lds, int tid) {
  const int lane = tid & 63, wave = tid >> 6;
#pragma unroll
  for (int c = 0; c < 2; ++c) {            // 8 KB tile = 8 chunks of 1 KB, 2/wave
    int chunk = wave * 2 + c;
    int off = chunk * 1024 + lane * 16;    // 64 B per row
    int r = off >> 6;
    int cb = off & 63;
    const char* g = gbase + (size_t)r * grow + cb;
    __builtin_amdgcn_global_load_lds(
        (__attribute__((address_space(1))) void*)g,
        (__attribute__((address_space(3))) void*)(lds + chunk * 1024),
        16, 0, 0);
  }
}

// ---- fragment load (A and B share layout: row = lane&15, k = quad*8+j) ----
__device__ __forceinline__ f16x8 load_frag16(const char* lds, int row, int kq) {
  return *(const f16x8*)(lds + ((size_t)row * 32 + kq) * 2);
}

// ---- generic 128x128 MFMA GEMM: C[m][n] = sum_k A[m][k]*B[n][k] (+epilogue) ----
// 2-phase double-buffered: stage(t+1) issued before compute(t); one barrier/iter.
template<int EPI>
__global__ __launch_bounds__(256, 2)
void gemm_k(const char* __restrict__ A, const char* __restrict__ B,
            int lda, int ldb, int K,
            char* __restrict__ C0,
            const float* __restrict__ bias, const float* __restrict__ resid) {
  __shared__ alignas(16) char smem[2][16384];   // [buf][A 8K | B 8K]

  const int tid = threadIdx.x, lane = tid & 63, wave = tid >> 6;
  const int wm = wave >> 1, wn = wave & 1;
  const int m0 = blockIdx.x * 128, n0 = blockIdx.y * 128;

  const char* pA = A; const char* pB = B;
  if constexpr (EPI == EPI_SCORES) {
    int z = blockIdx.z, h = z >> 2, b = z & 3;
    size_t e2 = ((size_t)b * 2048 * 4096 + (size_t)h * 512) * 2;
    pA += e2; pB += e2;
  } else if constexpr (EPI == EPI_CTX) {
    int z = blockIdx.z, h = z >> 2, b = z & 3;
    pA += ((size_t)z << 22) * 2;                       // atten16 block (f16)
    pB += ((size_t)(b * 8 + h) * 512 * 2048) * 2;      // vhT block (f16)
  }

  f32x4 acc[4][4];
#pragma unroll
  for (int i = 0; i < 4; ++i)
#pragma unroll
    for (int j = 0; j < 4; ++j) acc[i][j] = (f32x4){0.f, 0.f, 0.f, 0.f};

  const size_t rowA = (size_t)lda * 2, rowB = (size_t)ldb * 2;
  const char* gA = pA + (size_t)m0 * rowA;   // k advances by 64 B per K-step
  const char* gB = pB + (size_t)n0 * rowB;

  const int nk = K >> 5;
  const int kq = (lane >> 4) * 8, l15 = lane & 15, quad = lane >> 4;

  // prologue: stage tile 0
  stage_tile_f16(gA, rowA, smem[0], tid);
  stage_tile_f16(gB, rowB, smem[0] + 8192, tid);
  __syncthreads();   // drains vmcnt(0): buf0 ready

  for (int t = 0; t < nk; ++t) {
    char* cur = smem[t & 1];
    // issue next-tile loads FIRST (latency hides under ds_read+MFMA below)
    if (t + 1 < nk) {
      char* nxt = smem[(t + 1) & 1];
      stage_tile_f16(gA + (size_t)(t + 1) * 64, rowA, nxt, tid);
      stage_tile_f16(gB + (size_t)(t + 1) * 64, rowB, nxt + 8192, tid);
    }

    f16x8 af[4], bf[4];
#pragma unroll
    for (int mi = 0; mi < 4; ++mi)
      af[mi] = load_frag16(cur, wm * 64 + mi * 16 + l15, kq);
#pragma unroll
    for (int ni = 0; ni < 4; ++ni)
      bf[ni] = load_frag16(cur + 8192, wn * 64 + ni * 16 + l15, kq);

#pragma unroll
    for (int mi = 0; mi < 4; ++mi)
#pragma unroll
      for (int ni = 0; ni < 4; ++ni)
        acc[mi][ni] = mfma16(af[mi], bf[ni], acc[mi][ni]);

    __syncthreads();   // vmcnt(0)+lgkmcnt(0)+barrier: next buf ready, cur free
  }

  // epilogue: C/D layout col=lane&15, row=quad*4+reg (m89/m91-verified)
#pragma unroll
  for (int mi = 0; mi < 4; ++mi)
#pragma unroll
    for (int ni = 0; ni < 4; ++ni)
#pragma unroll
      for (int r = 0; r < 4; ++r) {
        int m = m0 + wm * 64 + mi * 16 + quad * 4 + r;
        int n = n0 + wn * 64 + ni * 16 + l15;
        float v = acc[mi][ni][r];
        if constexpr (EPI == EPI_QKH) {
          v += bias[n];
          ((f16*)C0)[(size_t)m * 4096 + n] = (f16)v;
        } else if constexpr (EPI == EPI_VHT) {
          v += bias[m];  // m is hd index
          int hh = m >> 9, d = m & 511, bb = n >> 11, ll = n & 2047;
          ((f16*)C0)[(((size_t)(bb * 8 + hh) * 512 + d) << 11) + ll] = (f16)v;
        } else if constexpr (EPI == EPI_SCORES) {
          int z = blockIdx.z;
          ((float*)C0)[((size_t)z << 22) + ((size_t)m << 11) + n] = v;
        } else if constexpr (EPI == EPI_CTX) {
          int z = blockIdx.z, hh = z >> 2, bb = z & 3;
          ((f16*)C0)[((size_t)(bb * 2048 + m) << 12) + hh * 512 + n] = (f16)v;
        } else {  // EPI_OUT
          v += bias[n] + resid[((size_t)m << 9) + n];
          ((float*)C0)[((size_t)m << 9) + n] = v;
        }
      }
}

// ---- weight transpose + f16 convert: out[c*rows+r] = in[r*cols+c] ----
__global__ __launch_bounds__(256)
void transpose_cvt_k(const float* __restrict__ in, f16* __restrict__ T,
                     int rows_in, int cols_in) {
  int idx = blockIdx.x * 256 + threadIdx.x;
  if (idx >= rows_in * cols_in) return;
  int c = idx / rows_in, r = idx - c * rows_in;
  T[idx] = (f16)in[(size_t)r * cols_in + c];
}

// ---- fp32 -> f16 elementwise (4 floats/thread) ----
__global__ __launch_bounds__(256)
void cvt_f16_k(const float* __restrict__ in, f16* __restrict__ out) {
  int i = blockIdx.x * 256 + threadIdx.x;
  float4 v = ((const float4*)in)[i];
  f16x4 h;
  h[0] = (f16)v.x; h[1] = (f16)v.y; h[2] = (f16)v.z; h[3] = (f16)v.w;
  ((f16x4*)out)[i] = h;
}

// ---- mask int32 -> int8 ----
__global__ __launch_bounds__(256)
void maskprep_k(const int* __restrict__ m32, unsigned char* __restrict__ m8) {
  int i = blockIdx.x * 256 + threadIdx.x;   // 4,194,304 int4s
  int4 v = ((const int4*)m32)[i];
  uchar4 c;
  c.x = (unsigned char)v.x; c.y = (unsigned char)v.y;
  c.z = (unsigned char)v.z; c.w = (unsigned char)v.w;
  ((uchar4*)m8)[i] = c;
}

// ---- masked in-place row softmax over 2048 cols, + f16 sidecar for PV ----
__global__ __launch_bounds__(256)
void softmax_k(float* __restrict__ att, const unsigned char* __restrict__ m8,
               f16* __restrict__ att16) {
  __shared__ float sm[4];
  int t = threadIdx.x, lane = t & 63, wave = t >> 6;
  size_t r = blockIdx.x;
  int z = (int)(r >> 11), m = (int)(r & 2047), b = z & 3;
  float4* row = (float4*)(att + (r << 11));
  const uchar4* mrow = (const uchar4*)(m8 + (((size_t)b << 22) + ((size_t)m << 11)));
  float4 a = row[t], c = row[t + 256];
  uchar4 ma = mrow[t], mc = mrow[t + 256];
  if (ma.x) a.x = -1e30f; if (ma.y) a.y = -1e30f;
  if (ma.z) a.z = -1e30f; if (ma.w) a.w = -1e30f;
  if (mc.x) c.x = -1e30f; if (mc.y) c.y = -1e30f;
  if (mc.z) c.z = -1e30f; if (mc.w) c.w = -1e30f;
  float mx = fmaxf(fmaxf(fmaxf(a.x, a.y), fmaxf(a.z, a.w)),
                   fmaxf(fmaxf(c.x, c.y), fmaxf(c.z, c.w)));
#pragma unroll
  for (int o = 32; o > 0; o >>= 1) mx = fmaxf(mx, __shfl_xor(mx, o));
  if (lane == 0) sm[wave] = mx;
  __syncthreads();
  mx = fmaxf(fmaxf(sm[0], sm[1]), fmaxf(sm[2], sm[3]));
  a.x = __expf(a.x - mx); a.y = __expf(a.y - mx);
  a.z = __expf(a.z - mx); a.w = __expf(a.w - mx);
  c.x = __expf(c.x - mx); c.y = __expf(c.y - mx);
  c.z = __expf(c.z - mx); c.w = __expf(c.w - mx);
  float s = a.x + a.y + a.z + a.w + c.x + c.y + c.z + c.w;
#pragma unroll
  for (int o = 32; o > 0; o >>= 1) s += __shfl_xor(s, o);
  __syncthreads();
  if (lane == 0) sm[wave] = s;
  __syncthreads();
  s = sm[0] + sm[1] + sm[2] + sm[3];
  float inv = 1.0f / s;
  a.x *= inv; a.y *= inv; a.z *= inv; a.w *= inv;
  c.x *= inv; c.y *= inv; c.z *= inv; c.w *= inv;
  row[t] = a; row[t + 256] = c;
  f16x4* r16 = (f16x4*)(att16 + (r << 11));
  f16x4 ha, hc;
  ha[0] = (f16)a.x; ha[1] = (f16)a.y; ha[2] = (f16)a.z; ha[3] = (f16)a.w;
  hc[0] = (f16)c.x; hc[1] = (f16)c.y; hc[2] = (f16)c.z; hc[3] = (f16)c.w;
  r16[t] = ha; r16[t + 256] = hc;
}

// ---- layernorm over last dim (512), biased var, eps=1e-5 ----
__global__ __launch_bounds__(256)
void ln_k(const float* __restrict__ x, const float* __restrict__ gamma,
          const float* __restrict__ beta, float* __restrict__ out) {
  __shared__ float s1[4], s2[4];
  int t = threadIdx.x, lane = t & 63, wave = t >> 6;
  size_t base = (size_t)blockIdx.x << 9;
  float2 v = ((const float2*)(x + base))[t];
  float s = v.x + v.y;
  float q = v.x * v.x + v.y * v.y;
#pragma unroll
  for (int o = 32; o > 0; o >>= 1) { s += __shfl_xor(s, o); q += __shfl_xor(q, o); }
  if (lane == 0) { s1[wave] = s; s2[wave] = q; }
  __syncthreads();
  s = s1[0] + s1[1] + s1[2] + s1[3];
  q = s2[0] + s2[1] + s2[2] + s2[3];
  float mu = s * (1.0f / 512.0f);
  float var = q * (1.0f / 512.0f) - mu * mu;
  float rs = rsqrtf(var + 1e-5f);
  float2 g = ((const float2*)gamma)[t];
  float2 bb = ((const float2*)beta)[t];
  float2 o2;
  o2.x = (v.x - mu) * rs * g.x + bb.x;
  o2.y = (v.y - mu) * rs * g.y + bb.y;
  ((float2*)(out + base))[t] = o2;
}

extern "C" void kernel_launch(void* const* d_in, const int* in_sizes, int n_in,
                              void* d_out, int out_size, void* d_ws, size_t ws_size,
                              hipStream_t stream) {
  (void)in_sizes; (void)n_in; (void)out_size; (void)ws_size;
  const float* q     = (const float*)d_in[0];
  const float* k     = (const float*)d_in[1];
  const float* v     = (const float*)d_in[2];
  const int*   mask  = (const int*)d_in[3];
  const float* Wq    = (const float*)d_in[4];
  const float* bq    = (const float*)d_in[5];
  const float* Wk    = (const float*)d_in[6];
  const float* bk    = (const float*)d_in[7];
  const float* Wv    = (const float*)d_in[8];
  const float* bv    = (const float*)d_in[9];
  const float* Wo    = (const float*)d_in[10];
  const float* bo    = (const float*)d_in[11];
  const float* gamma = (const float*)d_in[12];
  const float* beta  = (const float*)d_in[13];

  float* out0  = (float*)d_out;
  float* atten = out0 + (size_t)4 * 2048 * 512;

  char* ws = (char*)d_ws;
  const size_t MB = 1024ull * 1024ull;
  // liveness-packed layout (peak 440 MB):
  f16* WqT  = (f16*)(ws + 0 * MB);     // [4096x512] 4 MB
  f16* WkT  = (f16*)(ws + 4 * MB);
  f16* WvT  = (f16*)(ws + 8 * MB);
  f16* WoT  = (f16*)(ws + 12 * MB);    // [512x4096]
  unsigned char* mask8 = (unsigned char*)(ws + 16 * MB);  // 16 MB
  f16* q16  = (f16*)(ws + 32 * MB);    // 8 MB each, dead after projections
  f16* k16  = (f16*)(ws + 40 * MB);
  f16* v16  = (f16*)(ws + 48 * MB);
  f16* vhT  = (f16*)(ws + 56 * MB);    // [b][h][d][l] 64 MB, live thru PV
  f16* atten16 = (f16*)(ws + 120 * MB);// [z][l][l] 256 MB, softmax -> PV
  f16* qh   = (f16*)(ws + 120 * MB);   // 64 MB, dead before atten16 written
  f16* kh   = (f16*)(ws + 184 * MB);   // 64 MB, dead before atten16 written
  f16* ctx  = (f16*)(ws + 376 * MB);   // [8192x4096] 64 MB, ends 440 MB
  float* xbuf = (float*)(ws + 120 * MB); // 16 MB fp32, after atten16 dead

  // prep: weight transposes to NxK f16, mask to int8, q/k/v to f16
  transpose_cvt_k<<<8192, 256, 0, stream>>>(Wq, WqT, 512, 4096);
  transpose_cvt_k<<<8192, 256, 0, stream>>>(Wk, WkT, 512, 4096);
  transpose_cvt_k<<<8192, 256, 0, stream>>>(Wv, WvT, 512, 4096);
  transpose_cvt_k<<<8192, 256, 0, stream>>>(Wo, WoT, 4096, 512);
  maskprep_k<<<16384, 256, 0, stream>>>(mask, mask8);
  cvt_f16_k<<<4096, 256, 0, stream>>>(q, q16);
  cvt_f16_k<<<4096, 256, 0, stream>>>(k, k16);
  cvt_f16_k<<<4096, 256, 0, stream>>>(v, v16);

  // Q/K projections -> f16
  gemm_k<EPI_QKH><<<dim3(64, 32, 1), 256, 0, stream>>>(
      (const char*)q16, (const char*)WqT, 512, 512, 512, (char*)qh, bq, nullptr);
  gemm_k<EPI_QKH><<<dim3(64, 32, 1), 256, 0, stream>>>(
      (const char*)k16, (const char*)WkT, 512, 512, 512, (char*)kh, bk, nullptr);

  // V projection, written directly transposed: vhT[b][h][d][l]
  gemm_k<EPI_VHT><<<dim3(32, 64, 1), 256, 0, stream>>>(
      (const char*)WvT, (const char*)v16, 512, 512, 512, (char*)vhT, bv, nullptr);

  // raw scores = qh @ kh^T per (h,b) -> d_out atten region (fp32)
  gemm_k<EPI_SCORES><<<dim3(16, 16, 32), 256, 0, stream>>>(
      (const char*)qh, (const char*)kh, 4096, 4096, 512, (char*)atten, nullptr, nullptr);

  // masked softmax in place on d_out + f16 sidecar for PV
  softmax_k<<<65536, 256, 0, stream>>>(atten, mask8, atten16);

  // ctx = atten16 @ vh per (h,b)
  gemm_k<EPI_CTX><<<dim3(16, 4, 32), 256, 0, stream>>>(
      (const char*)atten16, (const char*)vhT, 2048, 2048, 2048, (char*)ctx, nullptr, nullptr);

  // out = ctx @ Wo + bo + residual(q) -> xbuf
  gemm_k<EPI_OUT><<<dim3(64, 4, 1), 256, 0, stream>>>(
      (const char*)ctx, (const char*)WoT, 4096, 4096, 4096, (char*)xbuf, bo, q);

  // layernorm -> out0
  ln_k<<<8192, 256, 0, stream>>>(xbuf, gamma, beta, out0);
}

// Round 3
// 1535.460 us; speedup vs baseline: 1.0693x; 1.0181x over previous
//
#include <hip/hip_runtime.h>
#include <stdint.h>

// MHA forward: B=4, L=2048, C=512, H=8, D=512 (HD=4096), TEMP=1, EPS=1e-5
// outputs: out0 = layernorm(ctx@Wo + bo + q)  [4,2048,512] fp32
//          atten = softmax(mask(qh@khT))      [32,2048,2048] fp32
//
// R3 changes vs R2 (1563 us):
//   - GEMM: 3-buffer LDS ring (48 KB), 2-tile prefetch lead, raw s_barrier +
//     counted "s_waitcnt vmcnt(4)" (never drains to 0 in main loop) -- T4.
//   - s_setprio(1) around MFMA cluster -- T5.
//   - XCD-chunked block swizzle on (bx,by) within each z -- T1.
//   - coalesced LDS-tiled weight transposes (old ones: strided scalar reads).
//   - out-proj split-K x2 (z dim), partials summed in layernorm (no atomics).
// Numerics: MFMA inputs/epilogues bit-identical; one fp32 add re-associated.

typedef unsigned short u16;
typedef _Float16 f16;
typedef __attribute__((ext_vector_type(4))) _Float16 f16x4;
typedef __attribute__((ext_vector_type(8))) _Float16 f16x8;
typedef __attribute__((ext_vector_type(4))) float f32x4;

#define EPI_QKH    0
#define EPI_VHT    1
#define EPI_SCORES 2
#define EPI_CTX    3
#define EPI_OUT    4

__device__ __forceinline__ f32x4 mfma16(f16x8 a, f16x8 b, f32x4 c) {
  return __builtin_amdgcn_mfma_f32_16x16x32_f16(a, b, c, 0, 0, 0);
}

// ---- staging: f16 tile 128x32 row-major via global_load_lds (width 16) ----
// 2 loads/thread per 8 KB tile -> A+B tile pair = 4 vmcnt units/thread.
__device__ __forceinline__ void stage_tile_f16(const char* gbase, size_t grow, char* lds, int tid) {
  const int lane = tid & 63, wave = tid >> 6;
#pragma unroll
  for (int c = 0; c < 2; ++c) {            // 8 KB tile = 8 chunks of 1 KB, 2/wave
    int chunk = wave * 2 + c;
    int off = chunk * 1024 + lane * 16;    // 64 B per row
    int r = off >> 6;
    int cb = off & 63;
    const char* g = gbase + (size_t)r * grow + cb;
    __builtin_amdgcn_global_load_lds(
        (__attribute__((address_space(1))) void*)g,
        (__attribute__((address_space(3))) void*)(lds + chunk * 1024),
        16, 0, 0);
  }
}

// ---- fragment load (A and B share layout: row = lane&15, k = quad*8+j) ----
__device__ __forceinline__ f16x8 load_frag16(const char* lds, int row, int kq) {
  return *(const f16x8*)(lds + ((size_t)row * 32 + kq) * 2);
}

// ---- generic 128x128 MFMA GEMM: C[m][n] = sum_k A[m][k]*B[n][k] (+epilogue) ----
// 3-deep pipelined: stage(t+2) during compute(t); wait vmcnt(4) per K-step.
template<int EPI>
__global__ __launch_bounds__(256, 2)
void gemm_k(const char* __restrict__ A, const char* __restrict__ B,
            int lda, int ldb, int K,
            char* __restrict__ C0,
            const float* __restrict__ bias, const float* __restrict__ resid) {
  __shared__ alignas(16) char smem[3 * 16384];   // ring of 3 (A 8K | B 8K)

  const int tid = threadIdx.x, lane = tid & 63, wave = tid >> 6;
  const int wm = wave >> 1, wn = wave & 1;

  // T1: XCD-chunked swizzle of flattened (bx,by); all grids have nx*ny % 8 == 0.
  const int nx = gridDim.x, ny = gridDim.y;
  int id = blockIdx.x + nx * blockIdx.y;
  const int chunk = (nx * ny) >> 3;
  id = (id & 7) * chunk + (id >> 3);
  const int m0 = (id % nx) * 128, n0 = (id / nx) * 128;

  const char* pA = A; const char* pB = B;
  int kz = 0;
  if constexpr (EPI == EPI_SCORES) {
    int z = blockIdx.z, h = z >> 2, b = z & 3;
    size_t e2 = ((size_t)b * 2048 * 4096 + (size_t)h * 512) * 2;
    pA += e2; pB += e2;
  } else if constexpr (EPI == EPI_CTX) {
    int z = blockIdx.z, h = z >> 2, b = z & 3;
    pA += ((size_t)z << 22) * 2;                       // atten16 block (f16)
    pB += ((size_t)(b * 8 + h) * 512 * 2048) * 2;      // vhT block (f16)
  } else if constexpr (EPI == EPI_OUT) {
    kz = blockIdx.z;                                   // split-K half
    pA += (size_t)kz * 2048 * 2;
    pB += (size_t)kz * 2048 * 2;
  }

  f32x4 acc[4][4];
#pragma unroll
  for (int i = 0; i < 4; ++i)
#pragma unroll
    for (int j = 0; j < 4; ++j) acc[i][j] = (f32x4){0.f, 0.f, 0.f, 0.f};

  const size_t rowA = (size_t)lda * 2, rowB = (size_t)ldb * 2;
  const char* gA = pA + (size_t)m0 * rowA;   // k advances by 64 B per K-step
  const char* gB = pB + (size_t)n0 * rowB;

  const int nk = K >> 5;
  const int kq = (lane >> 4) * 8, l15 = lane & 15, quad = lane >> 4;

  // prologue: stage tiles 0 and 1 (8 loads/thread in flight)
  stage_tile_f16(gA, rowA, smem, tid);
  stage_tile_f16(gB, rowB, smem + 8192, tid);
  stage_tile_f16(gA + 64, rowA, smem + 16384, tid);
  stage_tile_f16(gB + 64, rowB, smem + 16384 + 8192, tid);

  int bc = 0;                                  // buffer of tile kt
  for (int kt = 0; kt < nk; ++kt) {
    // tile kt resident after this wait (kt+1's 4 loads stay in flight)
    if (kt + 1 < nk) { asm volatile("s_waitcnt vmcnt(4)" ::: "memory"); }
    else             { asm volatile("s_waitcnt vmcnt(0)" ::: "memory"); }
    __builtin_amdgcn_sched_barrier(0);
    __builtin_amdgcn_s_barrier();              // all waves: kt ready, kt-1 reads done
    __builtin_amdgcn_sched_barrier(0);

    if (kt + 2 < nk) {                         // stage kt+2 into buffer (kt+2)%3
      int b2 = bc + 2; if (b2 >= 3) b2 -= 3;
      char* nb = smem + b2 * 16384;
      stage_tile_f16(gA + (size_t)(kt + 2) * 64, rowA, nb, tid);
      stage_tile_f16(gB + (size_t)(kt + 2) * 64, rowB, nb + 8192, tid);
    }

    char* cur = smem + bc * 16384;
    f16x8 af[4], bf[4];
#pragma unroll
    for (int mi = 0; mi < 4; ++mi)
      af[mi] = load_frag16(cur, wm * 64 + mi * 16 + l15, kq);
#pragma unroll
    for (int ni = 0; ni < 4; ++ni)
      bf[ni] = load_frag16(cur + 8192, wn * 64 + ni * 16 + l15, kq);

    __builtin_amdgcn_s_setprio(1);
#pragma unroll
    for (int mi = 0; mi < 4; ++mi)
#pragma unroll
      for (int ni = 0; ni < 4; ++ni)
        acc[mi][ni] = mfma16(af[mi], bf[ni], acc[mi][ni]);
    __builtin_amdgcn_s_setprio(0);

    bc = (bc + 1 == 3) ? 0 : bc + 1;
  }

  // epilogue: C/D layout col=lane&15, row=quad*4+reg (m89/m91-verified)
#pragma unroll
  for (int mi = 0; mi < 4; ++mi)
#pragma unroll
    for (int ni = 0; ni < 4; ++ni)
#pragma unroll
      for (int r = 0; r < 4; ++r) {
        int m = m0 + wm * 64 + mi * 16 + quad * 4 + r;
        int n = n0 + wn * 64 + ni * 16 + l15;
        float v = acc[mi][ni][r];
        if constexpr (EPI == EPI_QKH) {
          v += bias[n];
          ((f16*)C0)[(size_t)m * 4096 + n] = (f16)v;
        } else if constexpr (EPI == EPI_VHT) {
          v += bias[m];  // m is hd index
          int hh = m >> 9, d = m & 511, bb = n >> 11, ll = n & 2047;
          ((f16*)C0)[(((size_t)(bb * 8 + hh) * 512 + d) << 11) + ll] = (f16)v;
        } else if constexpr (EPI == EPI_SCORES) {
          int z = blockIdx.z;
          ((float*)C0)[((size_t)z << 22) + ((size_t)m << 11) + n] = v;
        } else if constexpr (EPI == EPI_CTX) {
          int z = blockIdx.z, hh = z >> 2, bb = z & 3;
          ((f16*)C0)[((size_t)(bb * 2048 + m) << 12) + hh * 512 + n] = (f16)v;
        } else {  // EPI_OUT: split-K partial; z=0 carries bias+residual
          if (kz == 0) v += bias[n] + resid[((size_t)m << 9) + n];
          ((float*)C0)[(size_t)kz * 8192 * 512 + ((size_t)m << 9) + n] = v;
        }
      }
}

// ---- coalesced weight transpose + f16 convert: out[c][r] = in[r][c] ----
// in: [R][Cc] fp32; out: [Cc][R] f16. 32x32 LDS tiles, 256 threads (32x8).
__global__ __launch_bounds__(256)
void transpose_cvt_k(const float* __restrict__ in, f16* __restrict__ T,
                     int R, int Cc) {
  __shared__ f16 tile[32][33];
  const int t = threadIdx.x, tc = t & 31, tr = t >> 5;
  const int bx = blockIdx.x, by = blockIdx.y;   // bx: col-tile, by: row-tile
#pragma unroll
  for (int k = 0; k < 4; ++k) {
    int r = by * 32 + tr + k * 8;
    tile[tr + k * 8][tc] = (f16)in[(size_t)r * Cc + bx * 32 + tc];
  }
  __syncthreads();
#pragma unroll
  for (int k = 0; k < 4; ++k) {
    int c = bx * 32 + tr + k * 8;
    T[(size_t)c * R + by * 32 + tc] = tile[tc][tr + k * 8];
  }
}

// ---- fp32 -> f16 elementwise (4 floats/thread) ----
__global__ __launch_bounds__(256)
void cvt_f16_k(const float* __restrict__ in, f16* __restrict__ out) {
  int i = blockIdx.x * 256 + threadIdx.x;
  float4 v = ((const float4*)in)[i];
  f16x4 h;
  h[0] = (f16)v.x; h[1] = (f16)v.y; h[2] = (f16)v.z; h[3] = (f16)v.w;
  ((f16x4*)out)[i] = h;
}

// ---- mask int32 -> int8 ----
__global__ __launch_bounds__(256)
void maskprep_k(const int* __restrict__ m32, unsigned char* __restrict__ m8) {
  int i = blockIdx.x * 256 + threadIdx.x;   // 4,194,304 int4s
  int4 v = ((const int4*)m32)[i];
  uchar4 c;
  c.x = (unsigned char)v.x; c.y = (unsigned char)v.y;
  c.z = (unsigned char)v.z; c.w = (unsigned char)v.w;
  ((uchar4*)m8)[i] = c;
}

// ---- masked in-place row softmax over 2048 cols, + f16 sidecar for PV ----
__global__ __launch_bounds__(256)
void softmax_k(float* __restrict__ att, const unsigned char* __restrict__ m8,
               f16* __restrict__ att16) {
  __shared__ float sm[4];
  int t = threadIdx.x, lane = t & 63, wave = t >> 6;
  size_t r = blockIdx.x;
  int z = (int)(r >> 11), m = (int)(r & 2047), b = z & 3;
  float4* row = (float4*)(att + (r << 11));
  const uchar4* mrow = (const uchar4*)(m8 + (((size_t)b << 22) + ((size_t)m << 11)));
  float4 a = row[t], c = row[t + 256];
  uchar4 ma = mrow[t], mc = mrow[t + 256];
  if (ma.x) a.x = -1e30f; if (ma.y) a.y = -1e30f;
  if (ma.z) a.z = -1e30f; if (ma.w) a.w = -1e30f;
  if (mc.x) c.x = -1e30f; if (mc.y) c.y = -1e30f;
  if (mc.z) c.z = -1e30f; if (mc.w) c.w = -1e30f;
  float mx = fmaxf(fmaxf(fmaxf(a.x, a.y), fmaxf(a.z, a.w)),
                   fmaxf(fmaxf(c.x, c.y), fmaxf(c.z, c.w)));
#pragma unroll
  for (int o = 32; o > 0; o >>= 1) mx = fmaxf(mx, __shfl_xor(mx, o));
  if (lane == 0) sm[wave] = mx;
  __syncthreads();
  mx = fmaxf(fmaxf(sm[0], sm[1]), fmaxf(sm[2], sm[3]));
  a.x = __expf(a.x - mx); a.y = __expf(a.y - mx);
  a.z = __expf(a.z - mx); a.w = __expf(a.w - mx);
  c.x = __expf(c.x - mx); c.y = __expf(c.y - mx);
  c.z = __expf(c.z - mx); c.w = __expf(c.w - mx);
  float s = a.x + a.y + a.z + a.w + c.x + c.y + c.z + c.w;
#pragma unroll
  for (int o = 32; o > 0; o >>= 1) s += __shfl_xor(s, o);
  __syncthreads();
  if (lane == 0) sm[wave] = s;
  __syncthreads();
  s = sm[0] + sm[1] + sm[2] + sm[3];
  float inv = 1.0f / s;
  a.x *= inv; a.y *= inv; a.z *= inv; a.w *= inv;
  c.x *= inv; c.y *= inv; c.z *= inv; c.w *= inv;
  row[t] = a; row[t + 256] = c;
  f16x4* r16 = (f16x4*)(att16 + (r << 11));
  f16x4 ha, hc;
  ha[0] = (f16)a.x; ha[1] = (f16)a.y; ha[2] = (f16)a.z; ha[3] = (f16)a.w;
  hc[0] = (f16)c.x; hc[1] = (f16)c.y; hc[2] = (f16)c.z; hc[3] = (f16)c.w;
  r16[t] = ha; r16[t + 256] = hc;
}

// ---- layernorm over last dim (512); input = x0 + x1 (split-K partials) ----
__global__ __launch_bounds__(256)
void ln_k(const float* __restrict__ x0, const float* __restrict__ x1,
          const float* __restrict__ gamma, const float* __restrict__ beta,
          float* __restrict__ out) {
  __shared__ float s1[4], s2[4];
  int t = threadIdx.x, lane = t & 63, wave = t >> 6;
  size_t base = (size_t)blockIdx.x << 9;
  float2 va = ((const float2*)(x0 + base))[t];
  float2 vb = ((const float2*)(x1 + base))[t];
  float2 v; v.x = va.x + vb.x; v.y = va.y + vb.y;
  float s = v.x + v.y;
  float q = v.x * v.x + v.y * v.y;
#pragma unroll
  for (int o = 32; o > 0; o >>= 1) { s += __shfl_xor(s, o); q += __shfl_xor(q, o); }
  if (lane == 0) { s1[wave] = s; s2[wave] = q; }
  __syncthreads();
  s = s1[0] + s1[1] + s1[2] + s1[3];
  q = s2[0] + s2[1] + s2[2] + s2[3];
  float mu = s * (1.0f / 512.0f);
  float var = q * (1.0f / 512.0f) - mu * mu;
  float rs = rsqrtf(var + 1e-5f);
  float2 g = ((const float2*)gamma)[t];
  float2 bb = ((const float2*)beta)[t];
  float2 o2;
  o2.x = (v.x - mu) * rs * g.x + bb.x;
  o2.y = (v.y - mu) * rs * g.y + bb.y;
  ((float2*)(out + base))[t] = o2;
}

extern "C" void kernel_launch(void* const* d_in, const int* in_sizes, int n_in,
                              void* d_out, int out_size, void* d_ws, size_t ws_size,
                              hipStream_t stream) {
  (void)in_sizes; (void)n_in; (void)out_size; (void)ws_size;
  const float* q     = (const float*)d_in[0];
  const float* k     = (const float*)d_in[1];
  const float* v     = (const float*)d_in[2];
  const int*   mask  = (const int*)d_in[3];
  const float* Wq    = (const float*)d_in[4];
  const float* bq    = (const float*)d_in[5];
  const float* Wk    = (const float*)d_in[6];
  const float* bk    = (const float*)d_in[7];
  const float* Wv    = (const float*)d_in[8];
  const float* bv    = (const float*)d_in[9];
  const float* Wo    = (const float*)d_in[10];
  const float* bo    = (const float*)d_in[11];
  const float* gamma = (const float*)d_in[12];
  const float* beta  = (const float*)d_in[13];

  float* out0  = (float*)d_out;
  float* atten = out0 + (size_t)4 * 2048 * 512;

  char* ws = (char*)d_ws;
  const size_t MB = 1024ull * 1024ull;
  // liveness-packed layout (peak 440 MB):
  f16* WqT  = (f16*)(ws + 0 * MB);     // [4096x512] 4 MB
  f16* WkT  = (f16*)(ws + 4 * MB);
  f16* WvT  = (f16*)(ws + 8 * MB);
  f16* WoT  = (f16*)(ws + 12 * MB);    // [512x4096]
  unsigned char* mask8 = (unsigned char*)(ws + 16 * MB);  // 16 MB
  f16* q16  = (f16*)(ws + 32 * MB);    // 8 MB each, dead after projections
  f16* k16  = (f16*)(ws + 40 * MB);
  f16* v16  = (f16*)(ws + 48 * MB);
  f16* vhT  = (f16*)(ws + 56 * MB);    // [b][h][d][l] 64 MB, live thru PV
  f16* atten16 = (f16*)(ws + 120 * MB);// [z][l][l] 256 MB, softmax -> PV
  f16* qh   = (f16*)(ws + 120 * MB);   // 64 MB, dead before atten16 written
  f16* kh   = (f16*)(ws + 184 * MB);   // 64 MB, dead before atten16 written
  f16* ctx  = (f16*)(ws + 376 * MB);   // [8192x4096] 64 MB, ends 440 MB
  float* xbuf = (float*)(ws + 120 * MB); // 2x16 MB fp32 partials (atten16 dead)

  // prep: weight transposes to NxK f16, mask to int8, q/k/v to f16
  transpose_cvt_k<<<dim3(128, 16), 256, 0, stream>>>(Wq, WqT, 512, 4096);
  transpose_cvt_k<<<dim3(128, 16), 256, 0, stream>>>(Wk, WkT, 512, 4096);
  transpose_cvt_k<<<dim3(128, 16), 256, 0, stream>>>(Wv, WvT, 512, 4096);
  transpose_cvt_k<<<dim3(16, 128), 256, 0, stream>>>(Wo, WoT, 4096, 512);
  maskprep_k<<<16384, 256, 0, stream>>>(mask, mask8);
  cvt_f16_k<<<4096, 256, 0, stream>>>(q, q16);
  cvt_f16_k<<<4096, 256, 0, stream>>>(k, k16);
  cvt_f16_k<<<4096, 256, 0, stream>>>(v, v16);

  // Q/K projections -> f16
  gemm_k<EPI_QKH><<<dim3(64, 32, 1), 256, 0, stream>>>(
      (const char*)q16, (const char*)WqT, 512, 512, 512, (char*)qh, bq, nullptr);
  gemm_k<EPI_QKH><<<dim3(64, 32, 1), 256, 0, stream>>>(
      (const char*)k16, (const char*)WkT, 512, 512, 512, (char*)kh, bk, nullptr);

  // V projection, written directly transposed: vhT[b][h][d][l]
  gemm_k<EPI_VHT><<<dim3(32, 64, 1), 256, 0, stream>>>(
      (const char*)WvT, (const char*)v16, 512, 512, 512, (char*)vhT, bv, nullptr);

  // raw scores = qh @ kh^T per (h,b) -> d_out atten region (fp32)
  gemm_k<EPI_SCORES><<<dim3(16, 16, 32), 256, 0, stream>>>(
      (const char*)qh, (const char*)kh, 4096, 4096, 512, (char*)atten, nullptr, nullptr);

  // masked softmax in place on d_out + f16 sidecar for PV
  softmax_k<<<65536, 256, 0, stream>>>(atten, mask8, atten16);

  // ctx = atten16 @ vh per (h,b)
  gemm_k<EPI_CTX><<<dim3(16, 4, 32), 256, 0, stream>>>(
      (const char*)atten16, (const char*)vhT, 2048, 2048, 2048, (char*)ctx, nullptr, nullptr);

  // out = ctx @ Wo (+ bo + residual on z=0) -> xbuf partials, split-K x2
  gemm_k<EPI_OUT><<<dim3(64, 4, 2), 256, 0, stream>>>(
      (const char*)ctx, (const char*)WoT, 4096, 4096, 2048, (char*)xbuf, bo, q);

  // layernorm over summed partials -> out0
  ln_k<<<8192, 256, 0, stream>>>(xbuf, xbuf + (size_t)8192 * 512, gamma, beta, out0);
}

// Round 4
// 1495.187 us; speedup vs baseline: 1.0981x; 1.0269x over previous
//
#include <hip/hip_runtime.h>
#include <stdint.h>

// MHA forward: B=4, L=2048, C=512, H=8, D=512 (HD=4096), TEMP=1, EPS=1e-5
// outputs: out0 = layernorm(ctx@Wo + bo + q)  [4,2048,512] fp32
//          atten = softmax(mask(qh@khT))      [32,2048,2048] fp32
//
// R4 changes vs R3 (1535 us):
//   - NEW 256x256-tile GEMM (512 thr, 8 waves 2x4, per-wave 128x64 out,
//     acc[8][4]) for the 5 heavy GEMMs. Same 3-ring counted-vmcnt(4) sync
//     as R3 (verified), LDS 3x32KB=96KB, 1 block/CU, 2 waves/SIMD.
//     MFMA:ds_read per K-step 32:12 (vs 16:8) and 4x K-loop work per
//     prologue/epilogue -> tile-geometry lever, not schedule polish.
//   - out-proj (N=512) stays on the 128^2 kernel (grid >= 512 blocks).
// Numerics bit-identical (same per-output accumulation order).

typedef unsigned short u16;
typedef _Float16 f16;
typedef __attribute__((ext_vector_type(4))) _Float16 f16x4;
typedef __attribute__((ext_vector_type(8))) _Float16 f16x8;
typedef __attribute__((ext_vector_type(4))) float f32x4;

#define EPI_QKH    0
#define EPI_VHT    1
#define EPI_SCORES 2
#define EPI_CTX    3
#define EPI_OUT    4

__device__ __forceinline__ f32x4 mfma16(f16x8 a, f16x8 b, f32x4 c) {
  return __builtin_amdgcn_mfma_f32_16x16x32_f16(a, b, c, 0, 0, 0);
}

// ---- staging: f16 tile (rows x 32) row-major via global_load_lds (width 16)
// works for 128-row tile w/ 4 waves (8 chunks) and 256-row tile w/ 8 waves
// (16 chunks): 2 loads/thread either way.
__device__ __forceinline__ void stage_tile_f16(const char* gbase, size_t grow, char* lds, int tid) {
  const int lane = tid & 63, wave = tid >> 6;
#pragma unroll
  for (int c = 0; c < 2; ++c) {
    int chunk = wave * 2 + c;
    int off = chunk * 1024 + lane * 16;    // 64 B per row
    int r = off >> 6;
    int cb = off & 63;
    const char* g = gbase + (size_t)r * grow + cb;
    __builtin_amdgcn_global_load_lds(
        (__attribute__((address_space(1))) void*)g,
        (__attribute__((address_space(3))) void*)(lds + chunk * 1024),
        16, 0, 0);
  }
}

// ---- fragment load (A and B share layout: row = lane&15, k = quad*8+j) ----
__device__ __forceinline__ f16x8 load_frag16(const char* lds, int row, int kq) {
  return *(const f16x8*)(lds + ((size_t)row * 32 + kq) * 2);
}

// ==== 256x256-tile GEMM: C[m][n] = sum_k A[m][k]*B[n][k] (+epilogue) ====
// 3-deep ring, counted vmcnt(4), setprio, XCD-chunked swizzle.
template<int EPI>
__global__ __launch_bounds__(512, 2)
void gemm256_k(const char* __restrict__ A, const char* __restrict__ B,
               int lda, int ldb, int K,
               char* __restrict__ C0, const float* __restrict__ bias) {
  __shared__ alignas(16) char smem[3][32768];   // ring of 3 (A 16K | B 16K)

  const int tid = threadIdx.x, lane = tid & 63, wave = tid >> 6;
  const int wm = wave >> 2, wn = wave & 3;      // 2 x 4 waves

  const int nx = gridDim.x, ny = gridDim.y;
  int id = blockIdx.x + nx * blockIdx.y;
  const int chunk = (nx * ny) >> 3;             // all grids: nx*ny % 8 == 0
  id = (id & 7) * chunk + (id >> 3);
  const int m0 = (id % nx) * 256, n0 = (id / nx) * 256;

  const char* pA = A; const char* pB = B;
  if constexpr (EPI == EPI_SCORES) {
    int z = blockIdx.z, h = z >> 2, b = z & 3;
    size_t e2 = ((size_t)b * 2048 * 4096 + (size_t)h * 512) * 2;
    pA += e2; pB += e2;
  } else if constexpr (EPI == EPI_CTX) {
    int z = blockIdx.z, h = z >> 2, b = z & 3;
    pA += ((size_t)z << 22) * 2;                       // atten16 block (f16)
    pB += ((size_t)(b * 8 + h) * 512 * 2048) * 2;      // vhT block (f16)
  }

  f32x4 acc[8][4];
#pragma unroll
  for (int i = 0; i < 8; ++i)
#pragma unroll
    for (int j = 0; j < 4; ++j) acc[i][j] = (f32x4){0.f, 0.f, 0.f, 0.f};

  const size_t rowA = (size_t)lda * 2, rowB = (size_t)ldb * 2;
  const char* gA = pA + (size_t)m0 * rowA;   // k advances by 64 B per K-step
  const char* gB = pB + (size_t)n0 * rowB;

  const int nk = K >> 5;
  const int kq = (lane >> 4) * 8, l15 = lane & 15, quad = lane >> 4;

  // prologue: stage tiles 0 and 1 (8 loads/thread in flight)
  stage_tile_f16(gA, rowA, smem[0], tid);
  stage_tile_f16(gB, rowB, smem[0] + 16384, tid);
  stage_tile_f16(gA + 64, rowA, smem[1], tid);
  stage_tile_f16(gB + 64, rowB, smem[1] + 16384, tid);

  int bc = 0;
  for (int kt = 0; kt < nk; ++kt) {
    if (kt + 1 < nk) { asm volatile("s_waitcnt vmcnt(4)" ::: "memory"); }
    else             { asm volatile("s_waitcnt vmcnt(0)" ::: "memory"); }
    __builtin_amdgcn_sched_barrier(0);
    __builtin_amdgcn_s_barrier();
    __builtin_amdgcn_sched_barrier(0);

    if (kt + 2 < nk) {
      int b2 = bc + 2; if (b2 >= 3) b2 -= 3;
      char* nb = smem[b2];
      stage_tile_f16(gA + (size_t)(kt + 2) * 64, rowA, nb, tid);
      stage_tile_f16(gB + (size_t)(kt + 2) * 64, rowB, nb + 16384, tid);
    }

    char* cur = smem[bc];
    f16x8 af[8], bf[4];
#pragma unroll
    for (int mi = 0; mi < 8; ++mi)
      af[mi] = load_frag16(cur, wm * 128 + mi * 16 + l15, kq);
#pragma unroll
    for (int ni = 0; ni < 4; ++ni)
      bf[ni] = load_frag16(cur + 16384, wn * 64 + ni * 16 + l15, kq);

    __builtin_amdgcn_s_setprio(1);
#pragma unroll
    for (int mi = 0; mi < 8; ++mi)
#pragma unroll
      for (int ni = 0; ni < 4; ++ni)
        acc[mi][ni] = mfma16(af[mi], bf[ni], acc[mi][ni]);
    __builtin_amdgcn_s_setprio(0);

    bc = (bc + 1 == 3) ? 0 : bc + 1;
  }

  // epilogue: C/D layout col=lane&15, row=quad*4+reg
#pragma unroll
  for (int mi = 0; mi < 8; ++mi)
#pragma unroll
    for (int ni = 0; ni < 4; ++ni)
#pragma unroll
      for (int r = 0; r < 4; ++r) {
        int m = m0 + wm * 128 + mi * 16 + quad * 4 + r;
        int n = n0 + wn * 64 + ni * 16 + l15;
        float v = acc[mi][ni][r];
        if constexpr (EPI == EPI_QKH) {
          v += bias[n];
          ((f16*)C0)[(size_t)m * 4096 + n] = (f16)v;
        } else if constexpr (EPI == EPI_VHT) {
          v += bias[m];  // m is hd index
          int hh = m >> 9, d = m & 511, bb = n >> 11, ll = n & 2047;
          ((f16*)C0)[(((size_t)(bb * 8 + hh) * 512 + d) << 11) + ll] = (f16)v;
        } else if constexpr (EPI == EPI_SCORES) {
          int z = blockIdx.z;
          ((float*)C0)[((size_t)z << 22) + ((size_t)m << 11) + n] = v;
        } else if constexpr (EPI == EPI_CTX) {
          int z = blockIdx.z, hh = z >> 2, bb = z & 3;
          ((f16*)C0)[((size_t)(bb * 2048 + m) << 12) + hh * 512 + n] = (f16)v;
        }
      }
}

// ==== 128x128-tile GEMM (kept for out-proj only, split-K via z) ====
template<int EPI>
__global__ __launch_bounds__(256, 2)
void gemm_k(const char* __restrict__ A, const char* __restrict__ B,
            int lda, int ldb, int K,
            char* __restrict__ C0,
            const float* __restrict__ bias, const float* __restrict__ resid) {
  __shared__ alignas(16) char smem[3 * 16384];   // ring of 3 (A 8K | B 8K)

  const int tid = threadIdx.x, lane = tid & 63, wave = tid >> 6;
  const int wm = wave >> 1, wn = wave & 1;

  const int nx = gridDim.x, ny = gridDim.y;
  int id = blockIdx.x + nx * blockIdx.y;
  const int chunk = (nx * ny) >> 3;
  id = (id & 7) * chunk + (id >> 3);
  const int m0 = (id % nx) * 128, n0 = (id / nx) * 128;

  const char* pA = A; const char* pB = B;
  int kz = 0;
  if constexpr (EPI == EPI_OUT) {
    kz = blockIdx.z;                                   // split-K half
    pA += (size_t)kz * 2048 * 2;
    pB += (size_t)kz * 2048 * 2;
  }

  f32x4 acc[4][4];
#pragma unroll
  for (int i = 0; i < 4; ++i)
#pragma unroll
    for (int j = 0; j < 4; ++j) acc[i][j] = (f32x4){0.f, 0.f, 0.f, 0.f};

  const size_t rowA = (size_t)lda * 2, rowB = (size_t)ldb * 2;
  const char* gA = pA + (size_t)m0 * rowA;
  const char* gB = pB + (size_t)n0 * rowB;

  const int nk = K >> 5;
  const int kq = (lane >> 4) * 8, l15 = lane & 15, quad = lane >> 4;

  stage_tile_f16(gA, rowA, smem, tid);
  stage_tile_f16(gB, rowB, smem + 8192, tid);
  stage_tile_f16(gA + 64, rowA, smem + 16384, tid);
  stage_tile_f16(gB + 64, rowB, smem + 16384 + 8192, tid);

  int bc = 0;
  for (int kt = 0; kt < nk; ++kt) {
    if (kt + 1 < nk) { asm volatile("s_waitcnt vmcnt(4)" ::: "memory"); }
    else             { asm volatile("s_waitcnt vmcnt(0)" ::: "memory"); }
    __builtin_amdgcn_sched_barrier(0);
    __builtin_amdgcn_s_barrier();
    __builtin_amdgcn_sched_barrier(0);

    if (kt + 2 < nk) {
      int b2 = bc + 2; if (b2 >= 3) b2 -= 3;
      char* nb = smem + b2 * 16384;
      stage_tile_f16(gA + (size_t)(kt + 2) * 64, rowA, nb, tid);
      stage_tile_f16(gB + (size_t)(kt + 2) * 64, rowB, nb + 8192, tid);
    }

    char* cur = smem + bc * 16384;
    f16x8 af[4], bf[4];
#pragma unroll
    for (int mi = 0; mi < 4; ++mi)
      af[mi] = load_frag16(cur, wm * 64 + mi * 16 + l15, kq);
#pragma unroll
    for (int ni = 0; ni < 4; ++ni)
      bf[ni] = load_frag16(cur + 8192, wn * 64 + ni * 16 + l15, kq);

    __builtin_amdgcn_s_setprio(1);
#pragma unroll
    for (int mi = 0; mi < 4; ++mi)
#pragma unroll
      for (int ni = 0; ni < 4; ++ni)
        acc[mi][ni] = mfma16(af[mi], bf[ni], acc[mi][ni]);
    __builtin_amdgcn_s_setprio(0);

    bc = (bc + 1 == 3) ? 0 : bc + 1;
  }

#pragma unroll
  for (int mi = 0; mi < 4; ++mi)
#pragma unroll
    for (int ni = 0; ni < 4; ++ni)
#pragma unroll
      for (int r = 0; r < 4; ++r) {
        int m = m0 + wm * 64 + mi * 16 + quad * 4 + r;
        int n = n0 + wn * 64 + ni * 16 + l15;
        float v = acc[mi][ni][r];
        if constexpr (EPI == EPI_OUT) {
          if (kz == 0) v += bias[n] + resid[((size_t)m << 9) + n];
          ((float*)C0)[(size_t)kz * 8192 * 512 + ((size_t)m << 9) + n] = v;
        }
      }
}

// ---- coalesced weight transpose + f16 convert: out[c][r] = in[r][c] ----
__global__ __launch_bounds__(256)
void transpose_cvt_k(const float* __restrict__ in, f16* __restrict__ T,
                     int R, int Cc) {
  __shared__ f16 tile[32][33];
  const int t = threadIdx.x, tc = t & 31, tr = t >> 5;
  const int bx = blockIdx.x, by = blockIdx.y;
#pragma unroll
  for (int k = 0; k < 4; ++k) {
    int r = by * 32 + tr + k * 8;
    tile[tr + k * 8][tc] = (f16)in[(size_t)r * Cc + bx * 32 + tc];
  }
  __syncthreads();
#pragma unroll
  for (int k = 0; k < 4; ++k) {
    int c = bx * 32 + tr + k * 8;
    T[(size_t)c * R + by * 32 + tc] = tile[tc][tr + k * 8];
  }
}

// ---- fp32 -> f16 elementwise (4 floats/thread) ----
__global__ __launch_bounds__(256)
void cvt_f16_k(const float* __restrict__ in, f16* __restrict__ out) {
  int i = blockIdx.x * 256 + threadIdx.x;
  float4 v = ((const float4*)in)[i];
  f16x4 h;
  h[0] = (f16)v.x; h[1] = (f16)v.y; h[2] = (f16)v.z; h[3] = (f16)v.w;
  ((f16x4*)out)[i] = h;
}

// ---- mask int32 -> int8 ----
__global__ __launch_bounds__(256)
void maskprep_k(const int* __restrict__ m32, unsigned char* __restrict__ m8) {
  int i = blockIdx.x * 256 + threadIdx.x;
  int4 v = ((const int4*)m32)[i];
  uchar4 c;
  c.x = (unsigned char)v.x; c.y = (unsigned char)v.y;
  c.z = (unsigned char)v.z; c.w = (unsigned char)v.w;
  ((uchar4*)m8)[i] = c;
}

// ---- masked in-place row softmax over 2048 cols, + f16 sidecar for PV ----
__global__ __launch_bounds__(256)
void softmax_k(float* __restrict__ att, const unsigned char* __restrict__ m8,
               f16* __restrict__ att16) {
  __shared__ float sm[4];
  int t = threadIdx.x, lane = t & 63, wave = t >> 6;
  size_t r = blockIdx.x;
  int z = (int)(r >> 11), m = (int)(r & 2047), b = z & 3;
  float4* row = (float4*)(att + (r << 11));
  const uchar4* mrow = (const uchar4*)(m8 + (((size_t)b << 22) + ((size_t)m << 11)));
  float4 a = row[t], c = row[t + 256];
  uchar4 ma = mrow[t], mc = mrow[t + 256];
  if (ma.x) a.x = -1e30f; if (ma.y) a.y = -1e30f;
  if (ma.z) a.z = -1e30f; if (ma.w) a.w = -1e30f;
  if (mc.x) c.x = -1e30f; if (mc.y) c.y = -1e30f;
  if (mc.z) c.z = -1e30f; if (mc.w) c.w = -1e30f;
  float mx = fmaxf(fmaxf(fmaxf(a.x, a.y), fmaxf(a.z, a.w)),
                   fmaxf(fmaxf(c.x, c.y), fmaxf(c.z, c.w)));
#pragma unroll
  for (int o = 32; o > 0; o >>= 1) mx = fmaxf(mx, __shfl_xor(mx, o));
  if (lane == 0) sm[wave] = mx;
  __syncthreads();
  mx = fmaxf(fmaxf(sm[0], sm[1]), fmaxf(sm[2], sm[3]));
  a.x = __expf(a.x - mx); a.y = __expf(a.y - mx);
  a.z = __expf(a.z - mx); a.w = __expf(a.w - mx);
  c.x = __expf(c.x - mx); c.y = __expf(c.y - mx);
  c.z = __expf(c.z - mx); c.w = __expf(c.w - mx);
  float s = a.x + a.y + a.z + a.w + c.x + c.y + c.z + c.w;
#pragma unroll
  for (int o = 32; o > 0; o >>= 1) s += __shfl_xor(s, o);
  __syncthreads();
  if (lane == 0) sm[wave] = s;
  __syncthreads();
  s = sm[0] + sm[1] + sm[2] + sm[3];
  float inv = 1.0f / s;
  a.x *= inv; a.y *= inv; a.z *= inv; a.w *= inv;
  c.x *= inv; c.y *= inv; c.z *= inv; c.w *= inv;
  row[t] = a; row[t + 256] = c;
  f16x4* r16 = (f16x4*)(att16 + (r << 11));
  f16x4 ha, hc;
  ha[0] = (f16)a.x; ha[1] = (f16)a.y; ha[2] = (f16)a.z; ha[3] = (f16)a.w;
  hc[0] = (f16)c.x; hc[1] = (f16)c.y; hc[2] = (f16)c.z; hc[3] = (f16)c.w;
  r16[t] = ha; r16[t + 256] = hc;
}

// ---- layernorm over last dim (512); input = x0 + x1 (split-K partials) ----
__global__ __launch_bounds__(256)
void ln_k(const float* __restrict__ x0, const float* __restrict__ x1,
          const float* __restrict__ gamma, const float* __restrict__ beta,
          float* __restrict__ out) {
  __shared__ float s1[4], s2[4];
  int t = threadIdx.x, lane = t & 63, wave = t >> 6;
  size_t base = (size_t)blockIdx.x << 9;
  float2 va = ((const float2*)(x0 + base))[t];
  float2 vb = ((const float2*)(x1 + base))[t];
  float2 v; v.x = va.x + vb.x; v.y = va.y + vb.y;
  float s = v.x + v.y;
  float q = v.x * v.x + v.y * v.y;
#pragma unroll
  for (int o = 32; o > 0; o >>= 1) { s += __shfl_xor(s, o); q += __shfl_xor(q, o); }
  if (lane == 0) { s1[wave] = s; s2[wave] = q; }
  __syncthreads();
  s = s1[0] + s1[1] + s1[2] + s1[3];
  q = s2[0] + s2[1] + s2[2] + s2[3];
  float mu = s * (1.0f / 512.0f);
  float var = q * (1.0f / 512.0f) - mu * mu;
  float rs = rsqrtf(var + 1e-5f);
  float2 g = ((const float2*)gamma)[t];
  float2 bb = ((const float2*)beta)[t];
  float2 o2;
  o2.x = (v.x - mu) * rs * g.x + bb.x;
  o2.y = (v.y - mu) * rs * g.y + bb.y;
  ((float2*)(out + base))[t] = o2;
}

extern "C" void kernel_launch(void* const* d_in, const int* in_sizes, int n_in,
                              void* d_out, int out_size, void* d_ws, size_t ws_size,
                              hipStream_t stream) {
  (void)in_sizes; (void)n_in; (void)out_size; (void)ws_size;
  const float* q     = (const float*)d_in[0];
  const float* k     = (const float*)d_in[1];
  const float* v     = (const float*)d_in[2];
  const int*   mask  = (const int*)d_in[3];
  const float* Wq    = (const float*)d_in[4];
  const float* bq    = (const float*)d_in[5];
  const float* Wk    = (const float*)d_in[6];
  const float* bk    = (const float*)d_in[7];
  const float* Wv    = (const float*)d_in[8];
  const float* bv    = (const float*)d_in[9];
  const float* Wo    = (const float*)d_in[10];
  const float* bo    = (const float*)d_in[11];
  const float* gamma = (const float*)d_in[12];
  const float* beta  = (const float*)d_in[13];

  float* out0  = (float*)d_out;
  float* atten = out0 + (size_t)4 * 2048 * 512;

  char* ws = (char*)d_ws;
  const size_t MB = 1024ull * 1024ull;
  f16* WqT  = (f16*)(ws + 0 * MB);
  f16* WkT  = (f16*)(ws + 4 * MB);
  f16* WvT  = (f16*)(ws + 8 * MB);
  f16* WoT  = (f16*)(ws + 12 * MB);
  unsigned char* mask8 = (unsigned char*)(ws + 16 * MB);
  f16* q16  = (f16*)(ws + 32 * MB);
  f16* k16  = (f16*)(ws + 40 * MB);
  f16* v16  = (f16*)(ws + 48 * MB);
  f16* vhT  = (f16*)(ws + 56 * MB);    // [b][h][d][l] 64 MB
  f16* atten16 = (f16*)(ws + 120 * MB);// 256 MB, softmax -> PV
  f16* qh   = (f16*)(ws + 120 * MB);   // 64 MB, dead before atten16 written
  f16* kh   = (f16*)(ws + 184 * MB);   // 64 MB, dead before atten16 written
  f16* ctx  = (f16*)(ws + 376 * MB);   // 64 MB, ends 440 MB
  float* xbuf = (float*)(ws + 120 * MB); // 2x16 MB fp32 partials

  transpose_cvt_k<<<dim3(128, 16), 256, 0, stream>>>(Wq, WqT, 512, 4096);
  transpose_cvt_k<<<dim3(128, 16), 256, 0, stream>>>(Wk, WkT, 512, 4096);
  transpose_cvt_k<<<dim3(128, 16), 256, 0, stream>>>(Wv, WvT, 512, 4096);
  transpose_cvt_k<<<dim3(16, 128), 256, 0, stream>>>(Wo, WoT, 4096, 512);
  maskprep_k<<<16384, 256, 0, stream>>>(mask, mask8);
  cvt_f16_k<<<4096, 256, 0, stream>>>(q, q16);
  cvt_f16_k<<<4096, 256, 0, stream>>>(k, k16);
  cvt_f16_k<<<4096, 256, 0, stream>>>(v, v16);

  // Q/K projections -> f16 (256-tile)
  gemm256_k<EPI_QKH><<<dim3(32, 16, 1), 512, 0, stream>>>(
      (const char*)q16, (const char*)WqT, 512, 512, 512, (char*)qh, bq);
  gemm256_k<EPI_QKH><<<dim3(32, 16, 1), 512, 0, stream>>>(
      (const char*)k16, (const char*)WkT, 512, 512, 512, (char*)kh, bk);

  // V projection, written directly transposed: vhT[b][h][d][l] (256-tile)
  gemm256_k<EPI_VHT><<<dim3(16, 32, 1), 512, 0, stream>>>(
      (const char*)WvT, (const char*)v16, 512, 512, 512, (char*)vhT, bv);

  // raw scores = qh @ kh^T per (h,b) -> d_out atten region (256-tile)
  gemm256_k<EPI_SCORES><<<dim3(8, 8, 32), 512, 0, stream>>>(
      (const char*)qh, (const char*)kh, 4096, 4096, 512, (char*)atten, nullptr);

  // masked softmax in place on d_out + f16 sidecar for PV
  softmax_k<<<65536, 256, 0, stream>>>(atten, mask8, atten16);

  // ctx = atten16 @ vh per (h,b) (256-tile)
  gemm256_k<EPI_CTX><<<dim3(8, 2, 32), 512, 0, stream>>>(
      (const char*)atten16, (const char*)vhT, 2048, 2048, 2048, (char*)ctx, nullptr);

  // out = ctx @ Wo (+ bo + residual on z=0) -> xbuf partials, split-K x2
  gemm_k<EPI_OUT><<<dim3(64, 4, 2), 256, 0, stream>>>(
      (const char*)ctx, (const char*)WoT, 4096, 4096, 2048, (char*)xbuf, bo, q);

  // layernorm over summed partials -> out0
  ln_k<<<8192, 256, 0, stream>>>(xbuf, xbuf + (size_t)8192 * 512, gamma, beta, out0);
}

// Round 5
// 1486.485 us; speedup vs baseline: 1.1045x; 1.0059x over previous
//
#include <hip/hip_runtime.h>
#include <stdint.h>

// MHA forward: B=4, L=2048, C=512, H=8, D=512 (HD=4096), TEMP=1, EPS=1e-5
// outputs: out0 = layernorm(ctx@Wo + bo + q)  [4,2048,512] fp32
//          atten = softmax(mask(qh@khT))      [32,2048,2048] fp32
//
// R5 vs R4 (1495 us): phased-pipeline 256x256 GEMM (T2+T3+T4 combo):
//   - BK=64, LDS 2 x (A 32K | B 32K) = 128 KB dbuf, 1 block/CU, 8 waves.
//   - 4 phases/K-tile: {stage 1 half-tile of t+1 || swizzled ds_reads ||
//     16 MFMA} + barrier. Counted vmcnt(2) once per K-tile (never 0 in loop).
//   - LDS XOR-swizzle byte^=((row&7)<<4): 16-way bank conflict -> ~2-way.
//     Applied as inverse-swizzled GLOBAL SOURCE + swizzled ds_read (linear
//     gload_lds dest), per both-sides-or-neither rule.
//   - stage lead 1.25 K-tiles; steady-state 10 vmem ops outstanding.
// Numerics bit-identical to R4 (same per-output accumulation order).

typedef unsigned short u16;
typedef _Float16 f16;
typedef __attribute__((ext_vector_type(4))) _Float16 f16x4;
typedef __attribute__((ext_vector_type(8))) _Float16 f16x8;
typedef __attribute__((ext_vector_type(4))) float f32x4;

#define EPI_QKH    0
#define EPI_VHT    1
#define EPI_SCORES 2
#define EPI_CTX    3
#define EPI_OUT    4

__device__ __forceinline__ f32x4 mfma16(f16x8 a, f16x8 b, f32x4 c) {
  return __builtin_amdgcn_mfma_f32_16x16x32_f16(a, b, c, 0, 0, 0);
}

// ---- stage one 128x64-f16 (16 KB) half-tile: LDS dest linear (gload_lds
// requires uniform-base + lane*16); global source inverse-swizzled so that
// swizzled ds_reads return the logical element. swz: c2 ^= ((row&7)<<4).
__device__ __forceinline__ void stage_half(const char* ghalf, size_t grow,
                                           char* ldshalf, int tid) {
#pragma unroll
  for (int c = 0; c < 2; ++c) {
    int d = c * 8192 + tid * 16;          // dest byte in 16KB half
    int r = d >> 7;                       // row 0..127 (128 B rows)
    int c2l = (d & 127) ^ ((r & 7) << 4); // involution: source col
    const char* g = ghalf + (size_t)r * grow + c2l;
    __builtin_amdgcn_global_load_lds(
        (__attribute__((address_space(1))) void*)g,
        (__attribute__((address_space(3))) void*)(ldshalf + d),
        16, 0, 0);
  }
}

// ---- swizzled fragment read: logical (row, kbyte) of a 128x64 f16 half ----
__device__ __forceinline__ f16x8 frag_swz(const char* ldshalf, int r, int kbyte) {
  return *(const f16x8*)(ldshalf + r * 128 + (kbyte ^ ((r & 7) << 4)));
}

// ==== phased 256x256 GEMM: C[m][n] = sum_k A[m][k]*B[n][k] (+epilogue) ====
template<int EPI>
__global__ __launch_bounds__(512, 2)
void gemm256p_k(const char* __restrict__ A, const char* __restrict__ B,
                int lda, int ldb, int K,
                char* __restrict__ C0, const float* __restrict__ bias) {
  // [buf][A0 16K | A1 16K | B0 16K | B1 16K]
  __shared__ alignas(16) char smem[2][65536];

  const int tid = threadIdx.x, lane = tid & 63, wave = tid >> 6;
  const int wm = wave >> 2, wn = wave & 3;        // 2 x 4 waves
  const int l15 = lane & 15, quad = lane >> 4;
  const int kb = quad * 16;                       // quad byte offset in K

  const int nx = gridDim.x, ny = gridDim.y;
  int id = blockIdx.x + nx * blockIdx.y;
  const int chunkw = (nx * ny) >> 3;              // all grids: nx*ny % 8 == 0
  id = (id & 7) * chunkw + (id >> 3);
  const int m0 = (id % nx) * 256, n0 = (id / nx) * 256;

  const char* pA = A; const char* pB = B;
  if constexpr (EPI == EPI_SCORES) {
    int z = blockIdx.z, h = z >> 2, b = z & 3;
    size_t e2 = ((size_t)b * 2048 * 4096 + (size_t)h * 512) * 2;
    pA += e2; pB += e2;
  } else if constexpr (EPI == EPI_CTX) {
    int z = blockIdx.z, h = z >> 2, b = z & 3;
    pA += ((size_t)z << 22) * 2;                  // atten16 block (f16)
    pB += ((size_t)(b * 8 + h) * 512 * 2048) * 2; // vhT block (f16)
  }

  f32x4 acc[8][4];
#pragma unroll
  for (int i = 0; i < 8; ++i)
#pragma unroll
    for (int j = 0; j < 4; ++j) acc[i][j] = (f32x4){0.f, 0.f, 0.f, 0.f};

  const size_t rowA = (size_t)lda * 2, rowB = (size_t)ldb * 2;
  const char* gA0 = pA + (size_t)m0 * rowA;       // A rows m0..m0+127
  const char* gA1 = gA0 + (size_t)128 * rowA;     // A rows m0+128..+255
  const char* gB0 = pB + (size_t)n0 * rowB;
  const char* gB1 = gB0 + (size_t)128 * rowB;

  const int nt = K >> 6;                          // K-tiles of 64 (128 B)

  // prologue: tile0 all 4 halves + A0(tile1): 10 vmem ops/thread in flight
  stage_half(gA0, rowA, smem[0],         tid);
  stage_half(gA1, rowA, smem[0] + 16384, tid);
  stage_half(gB0, rowB, smem[0] + 32768, tid);
  stage_half(gB1, rowB, smem[0] + 49152, tid);
  if (nt > 1) {
    stage_half(gA0 + 128, rowA, smem[1], tid);
    asm volatile("s_waitcnt vmcnt(2)" ::: "memory");   // tile0 retired
  } else {
    asm volatile("s_waitcnt vmcnt(0)" ::: "memory");
  }
  __builtin_amdgcn_sched_barrier(0);
  __builtin_amdgcn_s_barrier();
  __builtin_amdgcn_sched_barrier(0);

  for (int t = 0; t < nt; ++t) {
    char* cb = smem[t & 1];
    char* nb = smem[(t + 1) & 1];
    const char* myA = cb + wm * 16384;            // wave's A half
    const char* myB = cb + 32768 + (wn >> 1) * 16384;
    const int rb = (wn & 1) * 64;                 // B row base within half
    const size_t ko1 = (size_t)(t + 1) * 128;
    const size_t ko2 = (size_t)(t + 2) * 128;

    f16x8 a[8], b01[4], b23[4];

    // -- phase 0: stage A1(t+1) [dead since t-1 ph2]; read A(mi0-3)+B(ni0-1);
    //    MFMA quadrant (mi0-3 x ni0-1) --
    if (t + 1 < nt) stage_half(gA1 + ko1, rowA, nb + 16384, tid);
#pragma unroll
    for (int mi = 0; mi < 4; ++mi) {
      a[mi * 2]     = frag_swz(myA, mi * 16 + l15, kb);
      a[mi * 2 + 1] = frag_swz(myA, mi * 16 + l15, 64 + kb);
    }
#pragma unroll
    for (int ni = 0; ni < 2; ++ni) {
      b01[ni * 2]     = frag_swz(myB, rb + ni * 16 + l15, kb);
      b01[ni * 2 + 1] = frag_swz(myB, rb + ni * 16 + l15, 64 + kb);
    }
    __builtin_amdgcn_s_setprio(1);
#pragma unroll
    for (int mi = 0; mi < 4; ++mi)
#pragma unroll
      for (int ni = 0; ni < 2; ++ni) {
        acc[mi][ni] = mfma16(a[mi * 2],     b01[ni * 2],     acc[mi][ni]);
        acc[mi][ni] = mfma16(a[mi * 2 + 1], b01[ni * 2 + 1], acc[mi][ni]);
      }
    __builtin_amdgcn_s_setprio(0);
    __builtin_amdgcn_sched_barrier(0);
    __builtin_amdgcn_s_barrier();
    __builtin_amdgcn_sched_barrier(0);

    // -- phase 1: stage B0(t+1); read B(ni2-3); MFMA (mi0-3 x ni2-3) --
    if (t + 1 < nt) stage_half(gB0 + ko1, rowB, nb + 32768, tid);
#pragma unroll
    for (int ni = 0; ni < 2; ++ni) {
      b23[ni * 2]     = frag_swz(myB, rb + (ni + 2) * 16 + l15, kb);
      b23[ni * 2 + 1] = frag_swz(myB, rb + (ni + 2) * 16 + l15, 64 + kb);
    }
    __builtin_amdgcn_s_setprio(1);
#pragma unroll
    for (int mi = 0; mi < 4; ++mi)
#pragma unroll
      for (int ni = 0; ni < 2; ++ni) {
        acc[mi][ni + 2] = mfma16(a[mi * 2],     b23[ni * 2],     acc[mi][ni + 2]);
        acc[mi][ni + 2] = mfma16(a[mi * 2 + 1], b23[ni * 2 + 1], acc[mi][ni + 2]);
      }
    __builtin_amdgcn_s_setprio(0);
    __builtin_amdgcn_sched_barrier(0);
    __builtin_amdgcn_s_barrier();
    __builtin_amdgcn_sched_barrier(0);

    // -- phase 2: stage B1(t+1); read A(mi4-7); MFMA (mi4-7 x ni2-3) --
    if (t + 1 < nt) stage_half(gB1 + ko1, rowB, nb + 49152, tid);
#pragma unroll
    for (int mi = 0; mi < 4; ++mi) {
      a[mi * 2]     = frag_swz(myA, (mi + 4) * 16 + l15, kb);
      a[mi * 2 + 1] = frag_swz(myA, (mi + 4) * 16 + l15, 64 + kb);
    }
    __builtin_amdgcn_s_setprio(1);
#pragma unroll
    for (int mi = 0; mi < 4; ++mi)
#pragma unroll
      for (int ni = 0; ni < 2; ++ni) {
        acc[mi + 4][ni + 2] = mfma16(a[mi * 2],     b23[ni * 2],     acc[mi + 4][ni + 2]);
        acc[mi + 4][ni + 2] = mfma16(a[mi * 2 + 1], b23[ni * 2 + 1], acc[mi + 4][ni + 2]);
      }
    __builtin_amdgcn_s_setprio(0);
    __builtin_amdgcn_sched_barrier(0);
    __builtin_amdgcn_s_barrier();
    __builtin_amdgcn_sched_barrier(0);

    // -- phase 3: stage A0(t+2) into CURRENT buf (A0(t) dead since ph2);
    //    MFMA (mi4-7 x ni0-1); counted vmcnt retires tile t+1 --
    if (t + 2 < nt) stage_half(gA0 + ko2, rowA, cb, tid);
    __builtin_amdgcn_s_setprio(1);
#pragma unroll
    for (int mi = 0; mi < 4; ++mi)
#pragma unroll
      for (int ni = 0; ni < 2; ++ni) {
        acc[mi + 4][ni] = mfma16(a[mi * 2],     b01[ni * 2],     acc[mi + 4][ni]);
        acc[mi + 4][ni] = mfma16(a[mi * 2 + 1], b01[ni * 2 + 1], acc[mi + 4][ni]);
      }
    __builtin_amdgcn_s_setprio(0);
    if (t + 2 < nt) { asm volatile("s_waitcnt vmcnt(2)" ::: "memory"); }
    else            { asm volatile("s_waitcnt vmcnt(0)" ::: "memory"); }
    __builtin_amdgcn_sched_barrier(0);
    __builtin_amdgcn_s_barrier();
    __builtin_amdgcn_sched_barrier(0);
  }

  // epilogue: C/D layout col=lane&15, row=quad*4+reg (m89/m91-verified)
#pragma unroll
  for (int mi = 0; mi < 8; ++mi)
#pragma unroll
    for (int ni = 0; ni < 4; ++ni)
#pragma unroll
      for (int r = 0; r < 4; ++r) {
        int m = m0 + wm * 128 + mi * 16 + quad * 4 + r;
        int n = n0 + wn * 64 + ni * 16 + l15;
        float v = acc[mi][ni][r];
        if constexpr (EPI == EPI_QKH) {
          v += bias[n];
          ((f16*)C0)[(size_t)m * 4096 + n] = (f16)v;
        } else if constexpr (EPI == EPI_VHT) {
          v += bias[m];  // m is hd index
          int hh = m >> 9, d = m & 511, bb = n >> 11, ll = n & 2047;
          ((f16*)C0)[(((size_t)(bb * 8 + hh) * 512 + d) << 11) + ll] = (f16)v;
        } else if constexpr (EPI == EPI_SCORES) {
          int z = blockIdx.z;
          ((float*)C0)[((size_t)z << 22) + ((size_t)m << 11) + n] = v;
        } else if constexpr (EPI == EPI_CTX) {
          int z = blockIdx.z, hh = z >> 2, bb = z & 3;
          ((f16*)C0)[((size_t)(bb * 2048 + m) << 12) + hh * 512 + n] = (f16)v;
        }
      }
}

// ---- staging for 128^2 kernel: f16 tile 128x32 via global_load_lds ----
__device__ __forceinline__ void stage_tile_f16(const char* gbase, size_t grow, char* lds, int tid) {
  const int lane = tid & 63, wave = tid >> 6;
#pragma unroll
  for (int c = 0; c < 2; ++c) {
    int chunk = wave * 2 + c;
    int off = chunk * 1024 + lane * 16;
    int r = off >> 6;
    int cby = off & 63;
    const char* g = gbase + (size_t)r * grow + cby;
    __builtin_amdgcn_global_load_lds(
        (__attribute__((address_space(1))) void*)g,
        (__attribute__((address_space(3))) void*)(lds + chunk * 1024),
        16, 0, 0);
  }
}

__device__ __forceinline__ f16x8 load_frag16(const char* lds, int row, int kq) {
  return *(const f16x8*)(lds + ((size_t)row * 32 + kq) * 2);
}

// ==== 128x128-tile GEMM (out-proj only, split-K via z) ====
template<int EPI>
__global__ __launch_bounds__(256, 2)
void gemm_k(const char* __restrict__ A, const char* __restrict__ B,
            int lda, int ldb, int K,
            char* __restrict__ C0,
            const float* __restrict__ bias, const float* __restrict__ resid) {
  __shared__ alignas(16) char smem[3 * 16384];

  const int tid = threadIdx.x, lane = tid & 63, wave = tid >> 6;
  const int wm = wave >> 1, wn = wave & 1;

  const int nx = gridDim.x, ny = gridDim.y;
  int id = blockIdx.x + nx * blockIdx.y;
  const int chunk = (nx * ny) >> 3;
  id = (id & 7) * chunk + (id >> 3);
  const int m0 = (id % nx) * 128, n0 = (id / nx) * 128;

  const char* pA = A; const char* pB = B;
  int kz = 0;
  if constexpr (EPI == EPI_OUT) {
    kz = blockIdx.z;
    pA += (size_t)kz * 2048 * 2;
    pB += (size_t)kz * 2048 * 2;
  }

  f32x4 acc[4][4];
#pragma unroll
  for (int i = 0; i < 4; ++i)
#pragma unroll
    for (int j = 0; j < 4; ++j) acc[i][j] = (f32x4){0.f, 0.f, 0.f, 0.f};

  const size_t rowA = (size_t)lda * 2, rowB = (size_t)ldb * 2;
  const char* gA = pA + (size_t)m0 * rowA;
  const char* gB = pB + (size_t)n0 * rowB;

  const int nk = K >> 5;
  const int kq = (lane >> 4) * 8, l15 = lane & 15, quad = lane >> 4;

  stage_tile_f16(gA, rowA, smem, tid);
  stage_tile_f16(gB, rowB, smem + 8192, tid);
  stage_tile_f16(gA + 64, rowA, smem + 16384, tid);
  stage_tile_f16(gB + 64, rowB, smem + 16384 + 8192, tid);

  int bc = 0;
  for (int kt = 0; kt < nk; ++kt) {
    if (kt + 1 < nk) { asm volatile("s_waitcnt vmcnt(4)" ::: "memory"); }
    else             { asm volatile("s_waitcnt vmcnt(0)" ::: "memory"); }
    __builtin_amdgcn_sched_barrier(0);
    __builtin_amdgcn_s_barrier();
    __builtin_amdgcn_sched_barrier(0);

    if (kt + 2 < nk) {
      int b2 = bc + 2; if (b2 >= 3) b2 -= 3;
      char* nb = smem + b2 * 16384;
      stage_tile_f16(gA + (size_t)(kt + 2) * 64, rowA, nb, tid);
      stage_tile_f16(gB + (size_t)(kt + 2) * 64, rowB, nb + 8192, tid);
    }

    char* cur = smem + bc * 16384;
    f16x8 af[4], bf[4];
#pragma unroll
    for (int mi = 0; mi < 4; ++mi)
      af[mi] = load_frag16(cur, wm * 64 + mi * 16 + l15, kq);
#pragma unroll
    for (int ni = 0; ni < 4; ++ni)
      bf[ni] = load_frag16(cur + 8192, wn * 64 + ni * 16 + l15, kq);

    __builtin_amdgcn_s_setprio(1);
#pragma unroll
    for (int mi = 0; mi < 4; ++mi)
#pragma unroll
      for (int ni = 0; ni < 4; ++ni)
        acc[mi][ni] = mfma16(af[mi], bf[ni], acc[mi][ni]);
    __builtin_amdgcn_s_setprio(0);

    bc = (bc + 1 == 3) ? 0 : bc + 1;
  }

#pragma unroll
  for (int mi = 0; mi < 4; ++mi)
#pragma unroll
    for (int ni = 0; ni < 4; ++ni)
#pragma unroll
      for (int r = 0; r < 4; ++r) {
        int m = m0 + wm * 64 + mi * 16 + quad * 4 + r;
        int n = n0 + wn * 64 + ni * 16 + l15;
        float v = acc[mi][ni][r];
        if constexpr (EPI == EPI_OUT) {
          if (kz == 0) v += bias[n] + resid[((size_t)m << 9) + n];
          ((float*)C0)[(size_t)kz * 8192 * 512 + ((size_t)m << 9) + n] = v;
        }
      }
}

// ---- coalesced weight transpose + f16 convert: out[c][r] = in[r][c] ----
__global__ __launch_bounds__(256)
void transpose_cvt_k(const float* __restrict__ in, f16* __restrict__ T,
                     int R, int Cc) {
  __shared__ f16 tile[32][33];
  const int t = threadIdx.x, tc = t & 31, tr = t >> 5;
  const int bx = blockIdx.x, by = blockIdx.y;
#pragma unroll
  for (int k = 0; k < 4; ++k) {
    int r = by * 32 + tr + k * 8;
    tile[tr + k * 8][tc] = (f16)in[(size_t)r * Cc + bx * 32 + tc];
  }
  __syncthreads();
#pragma unroll
  for (int k = 0; k < 4; ++k) {
    int c = bx * 32 + tr + k * 8;
    T[(size_t)c * R + by * 32 + tc] = tile[tc][tr + k * 8];
  }
}

// ---- fp32 -> f16 elementwise (4 floats/thread) ----
__global__ __launch_bounds__(256)
void cvt_f16_k(const float* __restrict__ in, f16* __restrict__ out) {
  int i = blockIdx.x * 256 + threadIdx.x;
  float4 v = ((const float4*)in)[i];
  f16x4 h;
  h[0] = (f16)v.x; h[1] = (f16)v.y; h[2] = (f16)v.z; h[3] = (f16)v.w;
  ((f16x4*)out)[i] = h;
}

// ---- mask int32 -> int8 ----
__global__ __launch_bounds__(256)
void maskprep_k(const int* __restrict__ m32, unsigned char* __restrict__ m8) {
  int i = blockIdx.x * 256 + threadIdx.x;
  int4 v = ((const int4*)m32)[i];
  uchar4 c;
  c.x = (unsigned char)v.x; c.y = (unsigned char)v.y;
  c.z = (unsigned char)v.z; c.w = (unsigned char)v.w;
  ((uchar4*)m8)[i] = c;
}

// ---- masked in-place row softmax over 2048 cols, + f16 sidecar for PV ----
__global__ __launch_bounds__(256)
void softmax_k(float* __restrict__ att, const unsigned char* __restrict__ m8,
               f16* __restrict__ att16) {
  __shared__ float sm[4];
  int t = threadIdx.x, lane = t & 63, wave = t >> 6;
  size_t r = blockIdx.x;
  int z = (int)(r >> 11), m = (int)(r & 2047), b = z & 3;
  float4* row = (float4*)(att + (r << 11));
  const uchar4* mrow = (const uchar4*)(m8 + (((size_t)b << 22) + ((size_t)m << 11)));
  float4 a = row[t], c = row[t + 256];
  uchar4 ma = mrow[t], mc = mrow[t + 256];
  if (ma.x) a.x = -1e30f; if (ma.y) a.y = -1e30f;
  if (ma.z) a.z = -1e30f; if (ma.w) a.w = -1e30f;
  if (mc.x) c.x = -1e30f; if (mc.y) c.y = -1e30f;
  if (mc.z) c.z = -1e30f; if (mc.w) c.w = -1e30f;
  float mx = fmaxf(fmaxf(fmaxf(a.x, a.y), fmaxf(a.z, a.w)),
                   fmaxf(fmaxf(c.x, c.y), fmaxf(c.z, c.w)));
#pragma unroll
  for (int o = 32; o > 0; o >>= 1) mx = fmaxf(mx, __shfl_xor(mx, o));
  if (lane == 0) sm[wave] = mx;
  __syncthreads();
  mx = fmaxf(fmaxf(sm[0], sm[1]), fmaxf(sm[2], sm[3]));
  a.x = __expf(a.x - mx); a.y = __expf(a.y - mx);
  a.z = __expf(a.z - mx); a.w = __expf(a.w - mx);
  c.x = __expf(c.x - mx); c.y = __expf(c.y - mx);
  c.z = __expf(c.z - mx); c.w = __expf(c.w - mx);
  float s = a.x + a.y + a.z + a.w + c.x + c.y + c.z + c.w;
#pragma unroll
  for (int o = 32; o > 0; o >>= 1) s += __shfl_xor(s, o);
  __syncthreads();
  if (lane == 0) sm[wave] = s;
  __syncthreads();
  s = sm[0] + sm[1] + sm[2] + sm[3];
  float inv = 1.0f / s;
  a.x *= inv; a.y *= inv; a.z *= inv; a.w *= inv;
  c.x *= inv; c.y *= inv; c.z *= inv; c.w *= inv;
  row[t] = a; row[t + 256] = c;
  f16x4* r16 = (f16x4*)(att16 + (r << 11));
  f16x4 ha, hc;
  ha[0] = (f16)a.x; ha[1] = (f16)a.y; ha[2] = (f16)a.z; ha[3] = (f16)a.w;
  hc[0] = (f16)c.x; hc[1] = (f16)c.y; hc[2] = (f16)c.z; hc[3] = (f16)c.w;
  r16[t] = ha; r16[t + 256] = hc;
}

// ---- layernorm over last dim (512); input = x0 + x1 (split-K partials) ----
__global__ __launch_bounds__(256)
void ln_k(const float* __restrict__ x0, const float* __restrict__ x1,
          const float* __restrict__ gamma, const float* __restrict__ beta,
          float* __restrict__ out) {
  __shared__ float s1[4], s2[4];
  int t = threadIdx.x, lane = t & 63, wave = t >> 6;
  size_t base = (size_t)blockIdx.x << 9;
  float2 va = ((const float2*)(x0 + base))[t];
  float2 vb = ((const float2*)(x1 + base))[t];
  float2 v; v.x = va.x + vb.x; v.y = va.y + vb.y;
  float s = v.x + v.y;
  float q = v.x * v.x + v.y * v.y;
#pragma unroll
  for (int o = 32; o > 0; o >>= 1) { s += __shfl_xor(s, o); q += __shfl_xor(q, o); }
  if (lane == 0) { s1[wave] = s; s2[wave] = q; }
  __syncthreads();
  s = s1[0] + s1[1] + s1[2] + s1[3];
  q = s2[0] + s2[1] + s2[2] + s2[3];
  float mu = s * (1.0f / 512.0f);
  float var = q * (1.0f / 512.0f) - mu * mu;
  float rs = rsqrtf(var + 1e-5f);
  float2 g = ((const float2*)gamma)[t];
  float2 bb = ((const float2*)beta)[t];
  float2 o2;
  o2.x = (v.x - mu) * rs * g.x + bb.x;
  o2.y = (v.y - mu) * rs * g.y + bb.y;
  ((float2*)(out + base))[t] = o2;
}

extern "C" void kernel_launch(void* const* d_in, const int* in_sizes, int n_in,
                              void* d_out, int out_size, void* d_ws, size_t ws_size,
                              hipStream_t stream) {
  (void)in_sizes; (void)n_in; (void)out_size; (void)ws_size;
  const float* q     = (const float*)d_in[0];
  const float* k     = (const float*)d_in[1];
  const float* v     = (const float*)d_in[2];
  const int*   mask  = (const int*)d_in[3];
  const float* Wq    = (const float*)d_in[4];
  const float* bq    = (const float*)d_in[5];
  const float* Wk    = (const float*)d_in[6];
  const float* bk    = (const float*)d_in[7];
  const float* Wv    = (const float*)d_in[8];
  const float* bv    = (const float*)d_in[9];
  const float* Wo    = (const float*)d_in[10];
  const float* bo    = (const float*)d_in[11];
  const float* gamma = (const float*)d_in[12];
  const float* beta  = (const float*)d_in[13];

  float* out0  = (float*)d_out;
  float* atten = out0 + (size_t)4 * 2048 * 512;

  char* ws = (char*)d_ws;
  const size_t MB = 1024ull * 1024ull;
  f16* WqT  = (f16*)(ws + 0 * MB);
  f16* WkT  = (f16*)(ws + 4 * MB);
  f16* WvT  = (f16*)(ws + 8 * MB);
  f16* WoT  = (f16*)(ws + 12 * MB);
  unsigned char* mask8 = (unsigned char*)(ws + 16 * MB);
  f16* q16  = (f16*)(ws + 32 * MB);
  f16* k16  = (f16*)(ws + 40 * MB);
  f16* v16  = (f16*)(ws + 48 * MB);
  f16* vhT  = (f16*)(ws + 56 * MB);    // [b][h][d][l] 64 MB
  f16* atten16 = (f16*)(ws + 120 * MB);// 256 MB, softmax -> PV
  f16* qh   = (f16*)(ws + 120 * MB);   // 64 MB, dead before atten16 written
  f16* kh   = (f16*)(ws + 184 * MB);   // 64 MB, dead before atten16 written
  f16* ctx  = (f16*)(ws + 376 * MB);   // 64 MB, ends 440 MB
  float* xbuf = (float*)(ws + 120 * MB); // 2x16 MB fp32 partials

  transpose_cvt_k<<<dim3(128, 16), 256, 0, stream>>>(Wq, WqT, 512, 4096);
  transpose_cvt_k<<<dim3(128, 16), 256, 0, stream>>>(Wk, WkT, 512, 4096);
  transpose_cvt_k<<<dim3(128, 16), 256, 0, stream>>>(Wv, WvT, 512, 4096);
  transpose_cvt_k<<<dim3(16, 128), 256, 0, stream>>>(Wo, WoT, 4096, 512);
  maskprep_k<<<16384, 256, 0, stream>>>(mask, mask8);
  cvt_f16_k<<<4096, 256, 0, stream>>>(q, q16);
  cvt_f16_k<<<4096, 256, 0, stream>>>(k, k16);
  cvt_f16_k<<<4096, 256, 0, stream>>>(v, v16);

  // Q/K projections -> f16 (phased 256-tile)
  gemm256p_k<EPI_QKH><<<dim3(32, 16, 1), 512, 0, stream>>>(
      (const char*)q16, (const char*)WqT, 512, 512, 512, (char*)qh, bq);
  gemm256p_k<EPI_QKH><<<dim3(32, 16, 1), 512, 0, stream>>>(
      (const char*)k16, (const char*)WkT, 512, 512, 512, (char*)kh, bk);

  // V projection, written directly transposed: vhT[b][h][d][l]
  gemm256p_k<EPI_VHT><<<dim3(16, 32, 1), 512, 0, stream>>>(
      (const char*)WvT, (const char*)v16, 512, 512, 512, (char*)vhT, bv);

  // raw scores = qh @ kh^T per (h,b) -> d_out atten region
  gemm256p_k<EPI_SCORES><<<dim3(8, 8, 32), 512, 0, stream>>>(
      (const char*)qh, (const char*)kh, 4096, 4096, 512, (char*)atten, nullptr);

  // masked softmax in place on d_out + f16 sidecar for PV
  softmax_k<<<65536, 256, 0, stream>>>(atten, mask8, atten16);

  // ctx = atten16 @ vh per (h,b)
  gemm256p_k<EPI_CTX><<<dim3(8, 2, 32), 512, 0, stream>>>(
      (const char*)atten16, (const char*)vhT, 2048, 2048, 2048, (char*)ctx, nullptr);

  // out = ctx @ Wo (+ bo + residual on z=0) -> xbuf partials, split-K x2
  gemm_k<EPI_OUT><<<dim3(64, 4, 2), 256, 0, stream>>>(
      (const char*)ctx, (const char*)WoT, 4096, 4096, 2048, (char*)xbuf, bo, q);

  // layernorm over summed partials -> out0
  ln_k<<<8192, 256, 0, stream>>>(xbuf, xbuf + (size_t)8192 * 512, gamma, beta, out0);
}